// Round 1
// baseline (325.758 us; speedup 1.0000x reference)
//
#include <hip/hip_runtime.h>
#include <math.h>

#define B_  2
#define T_  12
#define N_  2048
#define D_  64
#define DI_ 128
#define DS_ 8
#define NM_ 10
#define CK_ 3
#define CS_ 2
#define TC_ 5
#define TT_ 17
#define L_  (T_*N_)        // 24576
#define CHUNK_ 64
#define NCH_ (L_/CHUNK_)   // 384

// ---------------- K0: fold small weight products ----------------
__global__ void k0_precomp(const float* __restrict__ msam_Wq, const float* __restrict__ msam_Mk,
                           const float* __restrict__ mem_Wq, const float* __restrict__ mem_M,
                           const float* __restrict__ mem_Wo,
                           float* __restrict__ W1, float* __restrict__ W1m, float* __restrict__ W2m) {
  int d = threadIdx.x;
  if (d >= 64) return;
  for (int m = 0; m < NM_; ++m) {
    float a = 0.f;
    for (int j = 0; j < 4; ++j) a += msam_Wq[d*4+j] * msam_Mk[m*4+j];
    W1[d*10+m] = a;
    float b = 0.f;
    for (int k = 0; k < 64; ++k) b += mem_Wq[d*64+k] * mem_M[m*64+k];
    W1m[d*10+m] = b;
    float c = 0.f;
    for (int k = 0; k < 64; ++k) c += mem_M[m*64+k] * mem_Wo[k*64+d];
    W2m[m*64+d] = c;
  }
}

// ---------------- K1: msam conv (stride 2) + 10-way attention ----------------
__global__ __launch_bounds__(256) void k1_msam(const float* __restrict__ x,
    const float* __restrict__ cw, const float* __restrict__ cb,
    const float* __restrict__ Mv, const float* __restrict__ W1,
    float* __restrict__ conv_out) {
  __shared__ float w_lds[CK_*64*64];   // 48 KB
  __shared__ float mv_lds[NM_*64];
  __shared__ float w1_lds[64*NM_];
  __shared__ float xrow[4][3][64];
  __shared__ float crow[4][64];
  __shared__ float lg[4][NM_];
  int tid = threadIdx.x;
  for (int i = tid; i < CK_*64*64; i += 256) w_lds[i] = cw[i];
  for (int i = tid; i < NM_*64; i += 256) { mv_lds[i] = Mv[i]; w1_lds[i] = W1[i]; }
  __syncthreads();
  int warp = tid >> 6, lane = tid & 63;
  for (int r = 0; r < 4; ++r) {
    int row = blockIdx.x*16 + warp*4 + r;     // 0..20479
    int b = row / (TC_*N_); int rem = row % (TC_*N_);
    int tc = rem / N_; int n = rem % N_;
    for (int k = 0; k < 3; ++k)
      xrow[warp][k][lane] = x[(((size_t)b*T_ + (2*tc+k))*N_ + n)*64 + lane];
    __syncthreads();
    float cv = cb[lane];
    #pragma unroll
    for (int k = 0; k < 3; ++k)
      for (int di = 0; di < 64; ++di)
        cv += xrow[warp][k][di] * w_lds[(k*64+di)*64 + lane];
    crow[warp][lane] = cv;
    __syncthreads();
    if (lane < NM_) {
      float a = 0.f;
      for (int dd = 0; dd < 64; ++dd) a += crow[warp][dd] * w1_lds[dd*10+lane];
      lg[warp][lane] = a;
    }
    __syncthreads();
    float lv[NM_], e[NM_];
    float mx = -1e30f;
    #pragma unroll
    for (int m = 0; m < NM_; ++m) { lv[m] = lg[warp][m]; mx = fmaxf(mx, lv[m]); }
    float ssum = 0.f;
    #pragma unroll
    for (int m = 0; m < NM_; ++m) { e[m] = __expf(lv[m]-mx); ssum += e[m]; }
    float inv = 1.f/ssum;
    float o = cv;
    #pragma unroll
    for (int m = 0; m < NM_; ++m) o += (e[m]*inv) * mv_lds[m*64+lane];
    conv_out[(((size_t)b*TC_+tc)*N_+n)*64 + lane] = o;
    __syncthreads();
  }
}

// ---------------- K2: memory attention over xcat ----------------
__global__ __launch_bounds__(256) void k2_mem(const float* __restrict__ x,
    const float* __restrict__ conv_out, const float* __restrict__ W1m,
    const float* __restrict__ W2m, float* __restrict__ memo) {
  __shared__ float w1_lds[640], w2_lds[640];
  __shared__ float rrow[4][64];
  __shared__ float lg[4][NM_];
  int tid = threadIdx.x;
  for (int i = tid; i < 640; i += 256) { w1_lds[i] = W1m[i]; w2_lds[i] = W2m[i]; }
  __syncthreads();
  int warp = tid >> 6, lane = tid & 63;
  for (int r = 0; r < 4; ++r) {
    int row = blockIdx.x*16 + warp*4 + r;    // 0..69631
    int b = row / (TT_*N_); int rem = row % (TT_*N_);
    int s = rem / N_; int n = rem % N_;
    float v = (s < T_) ? x[(((size_t)b*T_+s)*N_+n)*64 + lane]
                       : conv_out[(((size_t)b*TC_+(s-T_))*N_+n)*64 + lane];
    rrow[warp][lane] = v;
    __syncthreads();
    if (lane < NM_) {
      float a = 0.f;
      for (int dd = 0; dd < 64; ++dd) a += rrow[warp][dd] * w1_lds[dd*10+lane];
      lg[warp][lane] = a;
    }
    __syncthreads();
    float lv[NM_], e[NM_];
    float mx = -1e30f;
    #pragma unroll
    for (int m = 0; m < NM_; ++m) { lv[m] = lg[warp][m]; mx = fmaxf(mx, lv[m]); }
    float ssum = 0.f;
    #pragma unroll
    for (int m = 0; m < NM_; ++m) { e[m] = __expf(lv[m]-mx); ssum += e[m]; }
    float inv = 1.f/ssum;
    float o = 0.f;
    #pragma unroll
    for (int m = 0; m < NM_; ++m) o += (e[m]*inv) * w2_lds[m*64+lane];
    memo[(((size_t)b*TT_+s)*N_+n)*64 + lane] = o;
    __syncthreads();
  }
}

// ---------------- K3: time-mix einsum + residual + LayerNorm ----------------
__global__ __launch_bounds__(256) void k3_mix_ln(const float* __restrict__ x,
    const float* __restrict__ memo, const float* __restrict__ Wt,
    const float* __restrict__ ln_w, const float* __restrict__ ln_b,
    float* __restrict__ u, float* __restrict__ un) {
  __shared__ float wt[T_*TT_];
  int tid = threadIdx.x;
  for (int i = tid; i < T_*TT_; i += 256) wt[i] = Wt[i];
  __syncthreads();
  int wv = blockIdx.x*4 + (tid >> 6);   // 0..4095  (b,n)
  int lane = tid & 63;
  int b = wv / N_; int n = wv % N_;
  float ms[TT_];
  #pragma unroll
  for (int s = 0; s < TT_; ++s)
    ms[s] = memo[(((size_t)b*TT_+s)*N_+n)*64 + lane];
  float lw = ln_w[lane], lb = ln_b[lane];
  for (int t = 0; t < T_; ++t) {
    float acc = x[(((size_t)b*T_+t)*N_+n)*64 + lane];
    #pragma unroll
    for (int s = 0; s < TT_; ++s) acc += wt[t*TT_+s] * ms[s];
    size_t ro = ((size_t)b*L_ + (size_t)t*N_ + n)*64 + lane;
    u[ro] = acc;
    float s1 = acc, s2 = acc*acc;
    #pragma unroll
    for (int m = 1; m < 64; m <<= 1) { s1 += __shfl_xor(s1, m, 64); s2 += __shfl_xor(s2, m, 64); }
    float mu = s1 * (1.f/64.f);
    float var = s2 * (1.f/64.f) - mu*mu;
    float iv = rsqrtf(var + 1e-5f);
    un[ro] = (acc - mu) * iv * lw + lb;
  }
}

// ---------------- G1: in_proj GEMM (49152x64 @ 64x256), split into xm_raw/z ----------------
__global__ __launch_bounds__(256) void g1_inproj(const float* __restrict__ un,
    const float* __restrict__ W, float* __restrict__ xm_raw, float* __restrict__ z) {
  __shared__ float at[64][68];
  __shared__ float bt[64][68];
  int tid = threadIdx.x;
  int r0 = blockIdx.x*64; int j0 = blockIdx.y*64;
  for (int idx = tid; idx < 64*16; idx += 256) {
    int row = idx >> 4, c4 = idx & 15;
    float4 v = *(const float4*)&un[((size_t)(r0+row))*64 + c4*4];
    at[c4*4+0][row] = v.x; at[c4*4+1][row] = v.y; at[c4*4+2][row] = v.z; at[c4*4+3][row] = v.w;
  }
  for (int idx = tid; idx < 64*16; idx += 256) {
    int k = idx >> 4, j4 = idx & 15;
    *(float4*)&bt[k][j4*4] = *(const float4*)&W[(size_t)k*256 + j0 + j4*4];
  }
  __syncthreads();
  int ty = tid >> 4, tx = tid & 15;
  float acc[4][4] = {};
  for (int k = 0; k < 64; ++k) {
    float4 av = *(const float4*)&at[k][ty*4];
    float4 bv = *(const float4*)&bt[k][tx*4];
    acc[0][0] += av.x*bv.x; acc[0][1] += av.x*bv.y; acc[0][2] += av.x*bv.z; acc[0][3] += av.x*bv.w;
    acc[1][0] += av.y*bv.x; acc[1][1] += av.y*bv.y; acc[1][2] += av.y*bv.z; acc[1][3] += av.y*bv.w;
    acc[2][0] += av.z*bv.x; acc[2][1] += av.z*bv.y; acc[2][2] += av.z*bv.z; acc[2][3] += av.z*bv.w;
    acc[3][0] += av.w*bv.x; acc[3][1] += av.w*bv.y; acc[3][2] += av.w*bv.z; acc[3][3] += av.w*bv.w;
  }
  int cj = j0 + tx*4;
  float* dst; int col;
  if (cj < 128) { dst = xm_raw; col = cj; } else { dst = z; col = cj - 128; }
  #pragma unroll
  for (int i = 0; i < 4; ++i) {
    size_t row = r0 + ty*4 + i;
    float4 o; o.x = acc[i][0]; o.y = acc[i][1]; o.z = acc[i][2]; o.w = acc[i][3];
    *(float4*)&dst[row*128 + col] = o;
  }
}

// ---------------- K5: depthwise causal conv1d + silu + x_proj + dt ----------------
__global__ __launch_bounds__(256) void k5_conv_proj(const float* __restrict__ xm_raw,
    const float* __restrict__ cw, const float* __restrict__ cb,
    const float* __restrict__ xpw, const float* __restrict__ dtw, const float* __restrict__ dtb,
    float* __restrict__ xm, float* __restrict__ dt, float* __restrict__ Bm, float* __restrict__ Cm) {
  __shared__ float xp[DI_*20];
  __shared__ float xr[4][DI_];
  __shared__ float pj[4][20];
  int tid = threadIdx.x;
  for (int i = tid; i < DI_*20; i += 256) xp[i] = xpw[i];
  __syncthreads();
  int warp = tid >> 6, lane = tid & 63;
  int row = blockIdx.x*4 + warp;     // 0..49151
  int b = row / L_; int l = row % L_;
  size_t base = (size_t)row * DI_;
  #pragma unroll
  for (int h = 0; h < 2; ++h) {
    int ch = lane + h*64;
    float v = cb[ch];
    #pragma unroll
    for (int k = 0; k < 4; ++k) {
      int li = l - 3 + k;
      if (li >= 0) v += xm_raw[((size_t)b*L_ + li)*DI_ + ch] * cw[k*DI_+ch];
    }
    float sg = 1.f / (1.f + __expf(-v));
    v = v * sg;
    xm[base+ch] = v;
    xr[warp][ch] = v;
  }
  __syncthreads();
  if (lane < 20) {
    float a = 0.f;
    for (int c = 0; c < DI_; ++c) a += xr[warp][c] * xp[c*20+lane];
    pj[warp][lane] = a;
  }
  __syncthreads();
  #pragma unroll
  for (int h = 0; h < 2; ++h) {
    int ch = lane + h*64;
    float a = dtb[ch];
    #pragma unroll
    for (int j = 0; j < 4; ++j) a += pj[warp][j] * dtw[j*DI_+ch];
    float sp = (a > 20.f) ? a : log1pf(__expf(a));
    dt[base+ch] = sp;
  }
  if (lane < 8)       Bm[(size_t)row*8 + lane] = pj[warp][4+lane];
  else if (lane < 16) Cm[(size_t)row*8 + (lane-8)] = pj[warp][12+(lane-8)];
}

// ---------------- S1: per-chunk local scan aggregates ----------------
__global__ __launch_bounds__(256) void s1_scan_local(const float* __restrict__ dt,
    const float* __restrict__ xm, const float* __restrict__ Bm, const float* __restrict__ A_log,
    float* __restrict__ aggP, float* __restrict__ aggS) {
  int tid = threadIdx.x;
  int g = tid >> 7; int d = tid & 127;
  int chunkIdx = blockIdx.x*2 + g;
  int b = chunkIdx / NCH_; int ch = chunkIdx % NCH_;
  int l0 = ch * CHUNK_;
  float a[DS_];
  #pragma unroll
  for (int s = 0; s < DS_; ++s) a[s] = -__expf(A_log[d*DS_+s]);
  float P[DS_], S[DS_];
  #pragma unroll
  for (int s = 0; s < DS_; ++s) { P[s] = 1.f; S[s] = 0.f; }
  size_t rbase = (size_t)b*L_ + l0;
  for (int i = 0; i < CHUNK_; ++i) {
    size_t r = rbase + i;
    float dtv = dt[r*DI_ + d];
    float xmv = xm[r*DI_ + d];
    const float4* bp = (const float4*)&Bm[r*8];
    float4 b0 = bp[0], b1 = bp[1];
    float bv[8] = {b0.x,b0.y,b0.z,b0.w,b1.x,b1.y,b1.z,b1.w};
    float dx = dtv * xmv;
    #pragma unroll
    for (int s = 0; s < DS_; ++s) {
      float dA = __expf(dtv * a[s]);
      P[s] *= dA;
      S[s] = dA*S[s] + dx*bv[s];
    }
  }
  size_t o = (((size_t)b*NCH_ + ch)*128 + d)*8;
  float4 p0, p1, s0, s1v;
  p0.x=P[0];p0.y=P[1];p0.z=P[2];p0.w=P[3]; p1.x=P[4];p1.y=P[5];p1.z=P[6];p1.w=P[7];
  s0.x=S[0];s0.y=S[1];s0.z=S[2];s0.w=S[3]; s1v.x=S[4];s1v.y=S[5];s1v.z=S[6];s1v.w=S[7];
  *(float4*)&aggP[o] = p0; *(float4*)&aggP[o+4] = p1;
  *(float4*)&aggS[o] = s0; *(float4*)&aggS[o+4] = s1v;
}

// ---------------- S2: serial combine across chunks ----------------
__global__ __launch_bounds__(256) void s2_scan_chunks(const float* __restrict__ aggP,
    const float* __restrict__ aggS, float* __restrict__ hIn) {
  int gidx = blockIdx.x*256 + threadIdx.x;   // 0..2047 = (b, d*8+s)
  int b = gidx >> 10; int rem = gidx & 1023;
  float S = 0.f;
  #pragma unroll 4
  for (int ch = 0; ch < NCH_; ++ch) {
    size_t o = ((size_t)b*NCH_ + ch)*1024 + rem;
    hIn[o] = S;
    S = aggP[o]*S + aggS[o];
  }
}

// ---------------- S3: apply scan + y = sum_s h*C + xm*Dp, gate with silu(z) ----------------
__global__ __launch_bounds__(256) void s3_scan_apply(const float* __restrict__ dt,
    const float* __restrict__ xm, const float* __restrict__ Bm, const float* __restrict__ Cm,
    const float* __restrict__ z, const float* __restrict__ A_log, const float* __restrict__ Dp,
    const float* __restrict__ hIn, float* __restrict__ y2) {
  int tid = threadIdx.x;
  int g = tid >> 7; int d = tid & 127;
  int chunkIdx = blockIdx.x*2 + g;
  int b = chunkIdx / NCH_; int ch = chunkIdx % NCH_;
  int l0 = ch * CHUNK_;
  float a[DS_];
  #pragma unroll
  for (int s = 0; s < DS_; ++s) a[s] = -__expf(A_log[d*DS_+s]);
  float h[DS_];
  size_t o = (((size_t)b*NCH_ + ch)*128 + d)*8;
  #pragma unroll
  for (int s = 0; s < DS_; ++s) h[s] = hIn[o+s];
  float Dpd = Dp[d];
  size_t rbase = (size_t)b*L_ + l0;
  for (int i = 0; i < CHUNK_; ++i) {
    size_t r = rbase + i;
    float dtv = dt[r*DI_ + d];
    float xmv = xm[r*DI_ + d];
    float zv  = z[r*DI_ + d];
    const float4* bp = (const float4*)&Bm[r*8];
    const float4* cp = (const float4*)&Cm[r*8];
    float4 b0 = bp[0], b1 = bp[1], c0 = cp[0], c1 = cp[1];
    float bv[8] = {b0.x,b0.y,b0.z,b0.w,b1.x,b1.y,b1.z,b1.w};
    float cv[8] = {c0.x,c0.y,c0.z,c0.w,c1.x,c1.y,c1.z,c1.w};
    float dx = dtv * xmv;
    float yv = xmv * Dpd;
    #pragma unroll
    for (int s = 0; s < DS_; ++s) {
      float dA = __expf(dtv * a[s]);
      h[s] = dA*h[s] + dx*bv[s];
      yv += h[s]*cv[s];
    }
    float sg = 1.f / (1.f + __expf(-zv));
    y2[r*DI_ + d] = yv * zv * sg;
  }
}

// ---------------- G2: out_proj GEMM (49152x128 @ 128x64) + u residual -> d_out ----------------
__global__ __launch_bounds__(256) void g2_outproj(const float* __restrict__ y2,
    const float* __restrict__ W, const float* __restrict__ u, float* __restrict__ out) {
  __shared__ float at[128][68];
  __shared__ float bt[128][68];
  int tid = threadIdx.x;
  int r0 = blockIdx.x*64;
  for (int idx = tid; idx < 64*32; idx += 256) {
    int row = idx >> 5, c4 = idx & 31;
    float4 v = *(const float4*)&y2[((size_t)(r0+row))*128 + c4*4];
    at[c4*4+0][row] = v.x; at[c4*4+1][row] = v.y; at[c4*4+2][row] = v.z; at[c4*4+3][row] = v.w;
  }
  for (int idx = tid; idx < 128*16; idx += 256) {
    int k = idx >> 4, j4 = idx & 15;
    *(float4*)&bt[k][j4*4] = *(const float4*)&W[(size_t)k*64 + j4*4];
  }
  __syncthreads();
  int ty = tid >> 4, tx = tid & 15;
  float acc[4][4] = {};
  for (int k = 0; k < 128; ++k) {
    float4 av = *(const float4*)&at[k][ty*4];
    float4 bv = *(const float4*)&bt[k][tx*4];
    acc[0][0] += av.x*bv.x; acc[0][1] += av.x*bv.y; acc[0][2] += av.x*bv.z; acc[0][3] += av.x*bv.w;
    acc[1][0] += av.y*bv.x; acc[1][1] += av.y*bv.y; acc[1][2] += av.y*bv.z; acc[1][3] += av.y*bv.w;
    acc[2][0] += av.z*bv.x; acc[2][1] += av.z*bv.y; acc[2][2] += av.z*bv.z; acc[2][3] += av.z*bv.w;
    acc[3][0] += av.w*bv.x; acc[3][1] += av.w*bv.y; acc[3][2] += av.w*bv.z; acc[3][3] += av.w*bv.w;
  }
  #pragma unroll
  for (int i = 0; i < 4; ++i) {
    size_t row = r0 + ty*4 + i;
    int col = tx*4;
    float4 uv = *(const float4*)&u[row*64 + col];
    float4 o;
    o.x = uv.x + acc[i][0]; o.y = uv.y + acc[i][1]; o.z = uv.z + acc[i][2]; o.w = uv.w + acc[i][3];
    *(float4*)&out[row*64 + col] = o;
  }
}

// ---------------- launch ----------------
extern "C" void kernel_launch(void* const* d_in, const int* in_sizes, int n_in,
                              void* d_out, int out_size, void* d_ws, size_t ws_size,
                              hipStream_t stream) {
  const float* x        = (const float*)d_in[0];
  const float* mconv_w  = (const float*)d_in[1];
  const float* mconv_b  = (const float*)d_in[2];
  const float* mWq      = (const float*)d_in[3];
  const float* mMk      = (const float*)d_in[4];
  const float* mMv      = (const float*)d_in[5];
  const float* memWq    = (const float*)d_in[6];
  const float* memM     = (const float*)d_in[7];
  const float* memWo    = (const float*)d_in[8];
  const float* memWt    = (const float*)d_in[9];
  const float* ln_w     = (const float*)d_in[10];
  const float* ln_b     = (const float*)d_in[11];
  const float* in_proj  = (const float*)d_in[12];
  const float* conv1d_w = (const float*)d_in[13];
  const float* conv1d_b = (const float*)d_in[14];
  const float* x_proj   = (const float*)d_in[15];
  const float* dt_w     = (const float*)d_in[16];
  const float* dt_b     = (const float*)d_in[17];
  const float* A_log    = (const float*)d_in[18];
  const float* Dp       = (const float*)d_in[19];
  const float* out_proj = (const float*)d_in[20];
  float* out = (float*)d_out;
  float* ws  = (float*)d_ws;

  // workspace layout (floats)
  float* W1      = ws + 0;
  float* W1m     = ws + 640;
  float* W2m     = ws + 1280;
  float* conv_out= ws + 2048;                  // 1,310,720
  float* memo    = ws + 1312768;               // 4,456,448
  float* u       = ws + 5769216;               // 3,145,728
  float* un      = ws + 8914944;               // 3,145,728
  float* xm_raw  = ws + 12060672;              // 6,291,456 (reused as y2)
  float* z       = ws + 18352128;              // 6,291,456
  float* xm      = ws + 24643584;              // 6,291,456
  float* dt      = ws + 30935040;              // 6,291,456
  float* Bm      = ws + 37226496;              // 393,216
  float* Cm      = ws + 37619712;              // 393,216
  float* aggP    = ws + 38012928;              // 786,432
  float* aggS    = ws + 38799360;              // 786,432
  float* hIn     = ws + 39585792;              // 786,432
  float* y2      = xm_raw;                     // reuse

  hipLaunchKernelGGL(k0_precomp, dim3(1), dim3(64), 0, stream,
                     mWq, mMk, memWq, memM, memWo, W1, W1m, W2m);
  hipLaunchKernelGGL(k1_msam, dim3(1280), dim3(256), 0, stream,
                     x, mconv_w, mconv_b, mMv, W1, conv_out);
  hipLaunchKernelGGL(k2_mem, dim3(4352), dim3(256), 0, stream,
                     x, conv_out, W1m, W2m, memo);
  hipLaunchKernelGGL(k3_mix_ln, dim3(1024), dim3(256), 0, stream,
                     x, memo, memWt, ln_w, ln_b, u, un);
  hipLaunchKernelGGL(g1_inproj, dim3(768, 4), dim3(256), 0, stream,
                     un, in_proj, xm_raw, z);
  hipLaunchKernelGGL(k5_conv_proj, dim3(12288), dim3(256), 0, stream,
                     xm_raw, conv1d_w, conv1d_b, x_proj, dt_w, dt_b, xm, dt, Bm, Cm);
  hipLaunchKernelGGL(s1_scan_local, dim3(384), dim3(256), 0, stream,
                     dt, xm, Bm, A_log, aggP, aggS);
  hipLaunchKernelGGL(s2_scan_chunks, dim3(8), dim3(256), 0, stream,
                     aggP, aggS, hIn);
  hipLaunchKernelGGL(s3_scan_apply, dim3(384), dim3(256), 0, stream,
                     dt, xm, Bm, Cm, z, A_log, Dp, hIn, y2);
  hipLaunchKernelGGL(g2_outproj, dim3(768), dim3(256), 0, stream,
                     y2, out_proj, u, out);
}

// Round 2
// 272.991 us; speedup vs baseline: 1.1933x; 1.1933x over previous
//
#include <hip/hip_runtime.h>
#include <math.h>

#define B_  2
#define T_  12
#define N_  2048
#define D_  64
#define DI_ 128
#define DS_ 8
#define NM_ 10
#define CK_ 3
#define CS_ 2
#define TC_ 5
#define TT_ 17
#define L_  (T_*N_)        // 24576
#define CHUNK_ 64
#define NCH_ (L_/CHUNK_)   // 384

// ---------------- K0: fold small weight products ----------------
__global__ void k0_precomp(const float* __restrict__ msam_Wq, const float* __restrict__ msam_Mk,
                           const float* __restrict__ mem_Wq, const float* __restrict__ mem_M,
                           const float* __restrict__ mem_Wo,
                           float* __restrict__ W1, float* __restrict__ W1m, float* __restrict__ W2m) {
  int d = threadIdx.x;
  if (d >= 64) return;
  for (int m = 0; m < NM_; ++m) {
    float a = 0.f;
    for (int j = 0; j < 4; ++j) a += msam_Wq[d*4+j] * msam_Mk[m*4+j];
    W1[d*10+m] = a;
    float b = 0.f;
    for (int k = 0; k < 64; ++k) b += mem_Wq[d*64+k] * mem_M[m*64+k];
    W1m[d*10+m] = b;
    float c = 0.f;
    for (int k = 0; k < 64; ++k) c += mem_M[m*64+k] * mem_Wo[k*64+d];
    W2m[m*64+d] = c;
  }
}

// ---------------- K1a: msam conv as tiled fp32 GEMM (rows=n, K=192, cols=64) ----------------
__global__ __launch_bounds__(256) void k1a_conv(const float* __restrict__ x,
    const float* __restrict__ cw, const float* __restrict__ cb,
    float* __restrict__ conv_raw) {
  __shared__ float ats[64*65];      // A slab: [n][k-within-slab], pad 65
  __shared__ float bts[192*64];     // W: [K][c]
  int tid = threadIdx.x;
  int n0 = blockIdx.x * 64;
  int tc = blockIdx.y;
  int b  = blockIdx.z;
  for (int i = tid; i < 3072; i += 256)
    ((float4*)bts)[i] = ((const float4*)cw)[i];
  int ty = tid >> 4, tx = tid & 15;
  float acc[4][4] = {};
  for (int kk = 0; kk < 3; ++kk) {
    __syncthreads();
    const float* xs = x + (((size_t)b*T_ + (2*tc+kk))*N_ + n0)*64;
    for (int i = tid; i < 1024; i += 256) {
      int r = i >> 4, c = (i & 15) * 4;
      float4 v = ((const float4*)xs)[i];
      ats[r*65+c+0]=v.x; ats[r*65+c+1]=v.y; ats[r*65+c+2]=v.z; ats[r*65+c+3]=v.w;
    }
    __syncthreads();
    for (int k = 0; k < 64; ++k) {
      float a0 = ats[(ty*4+0)*65 + k];
      float a1 = ats[(ty*4+1)*65 + k];
      float a2 = ats[(ty*4+2)*65 + k];
      float a3 = ats[(ty*4+3)*65 + k];
      float4 bv = *(float4*)&bts[(kk*64+k)*64 + tx*4];
      acc[0][0]+=a0*bv.x; acc[0][1]+=a0*bv.y; acc[0][2]+=a0*bv.z; acc[0][3]+=a0*bv.w;
      acc[1][0]+=a1*bv.x; acc[1][1]+=a1*bv.y; acc[1][2]+=a1*bv.z; acc[1][3]+=a1*bv.w;
      acc[2][0]+=a2*bv.x; acc[2][1]+=a2*bv.y; acc[2][2]+=a2*bv.z; acc[2][3]+=a2*bv.w;
      acc[3][0]+=a3*bv.x; acc[3][1]+=a3*bv.y; acc[3][2]+=a3*bv.z; acc[3][3]+=a3*bv.w;
    }
  }
  float4 cbv = *(const float4*)&cb[tx*4];
  size_t rowbase = ((size_t)b*TC_ + tc)*N_ + n0;
  #pragma unroll
  for (int i = 0; i < 4; ++i) {
    float4 o;
    o.x = acc[i][0]+cbv.x; o.y = acc[i][1]+cbv.y; o.z = acc[i][2]+cbv.z; o.w = acc[i][3]+cbv.w;
    *(float4*)&conv_raw[(rowbase + ty*4+i)*64 + tx*4] = o;
  }
}

// ---------------- K1b: msam attention (lane=row transpose trick) ----------------
__global__ __launch_bounds__(256) void k1b_att(const float* __restrict__ conv_raw,
    const float* __restrict__ W1, const float* __restrict__ Mv,
    float* __restrict__ conv_out) {
  __shared__ float xt[4][64*66];
  __shared__ float w1T[10*66];
  int tid = threadIdx.x;
  for (int i = tid; i < 640; i += 256) {
    int c = i / 10, m = i % 10;
    w1T[m*66 + c] = W1[i];
  }
  int w = tid >> 6, lane = tid & 63;
  int R0 = blockIdx.x*256 + w*64;
  const float* src = conv_raw + (size_t)R0*64;
  float* xtw = xt[w];
  for (int it = 0; it < 16; ++it) {
    int flat = it*256 + lane*4;
    int r = flat >> 6, c = flat & 63;
    float4 v = *(const float4*)&src[(size_t)r*64 + c];
    xtw[r*66+c+0]=v.x; xtw[r*66+c+1]=v.y; xtw[r*66+c+2]=v.z; xtw[r*66+c+3]=v.w;
  }
  float w2r[10];
  #pragma unroll
  for (int j = 0; j < 10; ++j) w2r[j] = Mv[j*64 + lane];
  __syncthreads();
  // phase A: lane = row
  float p[10] = {};
  #pragma unroll 4
  for (int c2 = 0; c2 < 32; ++c2) {
    float2 v = *(float2*)&xtw[lane*66 + c2*2];
    #pragma unroll
    for (int j = 0; j < 10; ++j) {
      float2 wv = *(float2*)&w1T[j*66 + c2*2];
      p[j] += v.x*wv.x + v.y*wv.y;
    }
  }
  float m = p[0];
  #pragma unroll
  for (int j = 1; j < 10; ++j) m = fmaxf(m, p[j]);
  float att[10]; float ssum = 0.f;
  #pragma unroll
  for (int j = 0; j < 10; ++j) { att[j] = __expf(p[j]-m); ssum += att[j]; }
  float inv = 1.f/ssum;
  #pragma unroll
  for (int j = 0; j < 10; ++j) att[j] *= inv;
  // phase B: lane = channel; broadcast att via shfl
  float* dst = conv_out + (size_t)R0*64;
  for (int r = 0; r < 64; ++r) {
    float o = xtw[r*66 + lane];
    #pragma unroll
    for (int j = 0; j < 10; ++j) o += __shfl(att[j], r, 64) * w2r[j];
    dst[(size_t)r*64 + lane] = o;
  }
}

// ---------------- K2: memory attention (lane=row transpose trick) ----------------
__global__ __launch_bounds__(256) void k2_mem(const float* __restrict__ x,
    const float* __restrict__ conv_out, const float* __restrict__ W1m,
    const float* __restrict__ W2m, float* __restrict__ memo) {
  __shared__ float xt[4][64*66];
  __shared__ float w1T[10*66];
  int tid = threadIdx.x;
  for (int i = tid; i < 640; i += 256) {
    int c = i / 10, m = i % 10;
    w1T[m*66 + c] = W1m[i];
  }
  int w = tid >> 6, lane = tid & 63;
  int R0 = blockIdx.x*256 + w*64;
  int n0 = R0 & (N_-1);
  int sb = R0 >> 11;             // = b*TT_ + s
  int s  = sb % TT_;
  int b  = sb / TT_;
  const float* src = (s < T_) ? (x + (((size_t)b*T_ + s)*N_ + n0)*64)
                              : (conv_out + (((size_t)b*TC_ + (s-T_))*N_ + n0)*64);
  float* xtw = xt[w];
  for (int it = 0; it < 16; ++it) {
    int flat = it*256 + lane*4;
    int r = flat >> 6, c = flat & 63;
    float4 v = *(const float4*)&src[(size_t)r*64 + c];
    xtw[r*66+c+0]=v.x; xtw[r*66+c+1]=v.y; xtw[r*66+c+2]=v.z; xtw[r*66+c+3]=v.w;
  }
  float w2r[10];
  #pragma unroll
  for (int j = 0; j < 10; ++j) w2r[j] = W2m[j*64 + lane];
  __syncthreads();
  float p[10] = {};
  #pragma unroll 4
  for (int c2 = 0; c2 < 32; ++c2) {
    float2 v = *(float2*)&xtw[lane*66 + c2*2];
    #pragma unroll
    for (int j = 0; j < 10; ++j) {
      float2 wv = *(float2*)&w1T[j*66 + c2*2];
      p[j] += v.x*wv.x + v.y*wv.y;
    }
  }
  float m = p[0];
  #pragma unroll
  for (int j = 1; j < 10; ++j) m = fmaxf(m, p[j]);
  float att[10]; float ssum = 0.f;
  #pragma unroll
  for (int j = 0; j < 10; ++j) { att[j] = __expf(p[j]-m); ssum += att[j]; }
  float inv = 1.f/ssum;
  #pragma unroll
  for (int j = 0; j < 10; ++j) att[j] *= inv;
  float* dst = memo + (((size_t)b*TT_ + s)*N_ + n0)*64;
  for (int r = 0; r < 64; ++r) {
    float o = 0.f;
    #pragma unroll
    for (int j = 0; j < 10; ++j) o += __shfl(att[j], r, 64) * w2r[j];
    dst[(size_t)r*64 + lane] = o;
  }
}

// ---------------- K3: time-mix einsum + residual + LayerNorm ----------------
__global__ __launch_bounds__(256) void k3_mix_ln(const float* __restrict__ x,
    const float* __restrict__ memo, const float* __restrict__ Wt,
    const float* __restrict__ ln_w, const float* __restrict__ ln_b,
    float* __restrict__ u, float* __restrict__ un) {
  __shared__ float wt[T_*TT_];
  int tid = threadIdx.x;
  for (int i = tid; i < T_*TT_; i += 256) wt[i] = Wt[i];
  __syncthreads();
  int wv = blockIdx.x*4 + (tid >> 6);   // (b,n)
  int lane = tid & 63;
  int b = wv / N_; int n = wv % N_;
  float ms[TT_];
  #pragma unroll
  for (int s = 0; s < TT_; ++s)
    ms[s] = memo[(((size_t)b*TT_+s)*N_+n)*64 + lane];
  float lw = ln_w[lane], lb = ln_b[lane];
  for (int t = 0; t < T_; ++t) {
    float acc = x[(((size_t)b*T_+t)*N_+n)*64 + lane];
    #pragma unroll
    for (int s = 0; s < TT_; ++s) acc += wt[t*TT_+s] * ms[s];
    size_t ro = ((size_t)b*L_ + (size_t)t*N_ + n)*64 + lane;
    u[ro] = acc;
    float s1 = acc, s2 = acc*acc;
    #pragma unroll
    for (int m = 1; m < 64; m <<= 1) { s1 += __shfl_xor(s1, m, 64); s2 += __shfl_xor(s2, m, 64); }
    float mu = s1 * (1.f/64.f);
    float var = s2 * (1.f/64.f) - mu*mu;
    float iv = rsqrtf(var + 1e-5f);
    un[ro] = (acc - mu) * iv * lw + lb;
  }
}

// ---------------- G1: in_proj GEMM (49152x64 @ 64x256) ----------------
__global__ __launch_bounds__(256) void g1_inproj(const float* __restrict__ un,
    const float* __restrict__ W, float* __restrict__ xm_raw, float* __restrict__ z) {
  __shared__ float at[64][68];
  __shared__ float bt[64][68];
  int tid = threadIdx.x;
  int r0 = blockIdx.x*64; int j0 = blockIdx.y*64;
  for (int idx = tid; idx < 64*16; idx += 256) {
    int row = idx >> 4, c4 = idx & 15;
    float4 v = *(const float4*)&un[((size_t)(r0+row))*64 + c4*4];
    at[c4*4+0][row] = v.x; at[c4*4+1][row] = v.y; at[c4*4+2][row] = v.z; at[c4*4+3][row] = v.w;
  }
  for (int idx = tid; idx < 64*16; idx += 256) {
    int k = idx >> 4, j4 = idx & 15;
    *(float4*)&bt[k][j4*4] = *(const float4*)&W[(size_t)k*256 + j0 + j4*4];
  }
  __syncthreads();
  int ty = tid >> 4, tx = tid & 15;
  float acc[4][4] = {};
  for (int k = 0; k < 64; ++k) {
    float4 av = *(const float4*)&at[k][ty*4];
    float4 bv = *(const float4*)&bt[k][tx*4];
    acc[0][0] += av.x*bv.x; acc[0][1] += av.x*bv.y; acc[0][2] += av.x*bv.z; acc[0][3] += av.x*bv.w;
    acc[1][0] += av.y*bv.x; acc[1][1] += av.y*bv.y; acc[1][2] += av.y*bv.z; acc[1][3] += av.y*bv.w;
    acc[2][0] += av.z*bv.x; acc[2][1] += av.z*bv.y; acc[2][2] += av.z*bv.z; acc[2][3] += av.z*bv.w;
    acc[3][0] += av.w*bv.x; acc[3][1] += av.w*bv.y; acc[3][2] += av.w*bv.z; acc[3][3] += av.w*bv.w;
  }
  int cj = j0 + tx*4;
  float* dst; int col;
  if (cj < 128) { dst = xm_raw; col = cj; } else { dst = z; col = cj - 128; }
  #pragma unroll
  for (int i = 0; i < 4; ++i) {
    size_t row = r0 + ty*4 + i;
    float4 o; o.x = acc[i][0]; o.y = acc[i][1]; o.z = acc[i][2]; o.w = acc[i][3];
    *(float4*)&dst[row*128 + col] = o;
  }
}

// ---------------- K5: conv1d+silu+x_proj+dt, block = 64 rows ----------------
__global__ __launch_bounds__(256) void k5_conv_proj(const float* __restrict__ xm_raw,
    const float* __restrict__ cw, const float* __restrict__ cb,
    const float* __restrict__ xpw, const float* __restrict__ dtw, const float* __restrict__ dtb,
    float* __restrict__ xm, float* __restrict__ dt, float* __restrict__ Bm, float* __restrict__ Cm) {
  __shared__ float smemA[67*128];   // phase1: xs[67][128]; phase3: xv[64][132]
  __shared__ float xpT[20*132];
  __shared__ float pjs[64*21];
  int tid = threadIdx.x;
  int r0 = blockIdx.x * 64;
  int b = r0 / L_;
  int l0 = r0 % L_;
  const float* src = xm_raw + (size_t)b*L_*DI_;
  for (int i = tid; i < 2560; i += 256) {
    int c = i / 20, j = i % 20;
    xpT[j*132 + c] = xpw[i];
  }
  float4* xs4 = (float4*)smemA;
  for (int i = tid; i < 67*32; i += 256) {
    int lr = i >> 5, c4i = i & 31;
    int gl = l0 - 3 + lr;
    float4 v = make_float4(0.f,0.f,0.f,0.f);
    if (gl >= 0) v = *(const float4*)&src[(size_t)gl*DI_ + c4i*4];
    xs4[i] = v;
  }
  int cc4 = (tid & 31) * 4;
  int lhalf = tid >> 5;
  float4 w0 = *(const float4*)&cw[0*DI_ + cc4];
  float4 w1 = *(const float4*)&cw[1*DI_ + cc4];
  float4 w2 = *(const float4*)&cw[2*DI_ + cc4];
  float4 w3 = *(const float4*)&cw[3*DI_ + cc4];
  float4 cbv = *(const float4*)&cb[cc4];
  __syncthreads();
  float v[8][4];
  #pragma unroll
  for (int it = 0; it < 8; ++it) {
    int l = it*8 + lhalf;
    float4 t0 = xs4[(l+0)*32 + (tid&31)];
    float4 t1 = xs4[(l+1)*32 + (tid&31)];
    float4 t2 = xs4[(l+2)*32 + (tid&31)];
    float4 t3 = xs4[(l+3)*32 + (tid&31)];
    float a0 = cbv.x + t0.x*w0.x + t1.x*w1.x + t2.x*w2.x + t3.x*w3.x;
    float a1 = cbv.y + t0.y*w0.y + t1.y*w1.y + t2.y*w2.y + t3.y*w3.y;
    float a2 = cbv.z + t0.z*w0.z + t1.z*w1.z + t2.z*w2.z + t3.z*w3.z;
    float a3 = cbv.w + t0.w*w0.w + t1.w*w1.w + t2.w*w2.w + t3.w*w3.w;
    a0 = a0 / (1.f + __expf(-a0));
    a1 = a1 / (1.f + __expf(-a1));
    a2 = a2 / (1.f + __expf(-a2));
    a3 = a3 / (1.f + __expf(-a3));
    v[it][0]=a0; v[it][1]=a1; v[it][2]=a2; v[it][3]=a3;
    float4 sv; sv.x=a0; sv.y=a1; sv.z=a2; sv.w=a3;
    *(float4*)&xm[(size_t)(r0+l)*DI_ + cc4] = sv;
  }
  __syncthreads();
  float* xv = smemA;   // [64][132]
  #pragma unroll
  for (int it = 0; it < 8; ++it) {
    int l = it*8 + lhalf;
    float4 sv; sv.x=v[it][0]; sv.y=v[it][1]; sv.z=v[it][2]; sv.w=v[it][3];
    *(float4*)&xv[l*132 + cc4] = sv;
  }
  __syncthreads();
  {
    int row = tid >> 2, q = tid & 3, j0 = q*5;
    float acc[5] = {0,0,0,0,0};
    for (int k4 = 0; k4 < 32; ++k4) {
      float4 a4 = *(float4*)&xv[row*132 + k4*4];
      #pragma unroll
      for (int jj = 0; jj < 5; ++jj) {
        float4 b4 = *(float4*)&xpT[(j0+jj)*132 + k4*4];
        acc[jj] += a4.x*b4.x + a4.y*b4.y + a4.z*b4.z + a4.w*b4.w;
      }
    }
    #pragma unroll
    for (int jj = 0; jj < 5; ++jj) pjs[row*21 + j0+jj] = acc[jj];
  }
  __syncthreads();
  float4 dw0 = *(const float4*)&dtw[0*DI_ + cc4];
  float4 dw1 = *(const float4*)&dtw[1*DI_ + cc4];
  float4 dw2 = *(const float4*)&dtw[2*DI_ + cc4];
  float4 dw3 = *(const float4*)&dtw[3*DI_ + cc4];
  float4 dbv = *(const float4*)&dtb[cc4];
  #pragma unroll
  for (int it = 0; it < 8; ++it) {
    int l = it*8 + lhalf;
    float p0 = pjs[l*21+0], p1 = pjs[l*21+1], p2 = pjs[l*21+2], p3 = pjs[l*21+3];
    float a0 = dbv.x + p0*dw0.x + p1*dw1.x + p2*dw2.x + p3*dw3.x;
    float a1 = dbv.y + p0*dw0.y + p1*dw1.y + p2*dw2.y + p3*dw3.y;
    float a2 = dbv.z + p0*dw0.z + p1*dw1.z + p2*dw2.z + p3*dw3.z;
    float a3 = dbv.w + p0*dw0.w + p1*dw1.w + p2*dw2.w + p3*dw3.w;
    float4 sv;
    sv.x = (a0 > 20.f) ? a0 : log1pf(__expf(a0));
    sv.y = (a1 > 20.f) ? a1 : log1pf(__expf(a1));
    sv.z = (a2 > 20.f) ? a2 : log1pf(__expf(a2));
    sv.w = (a3 > 20.f) ? a3 : log1pf(__expf(a3));
    *(float4*)&dt[(size_t)(r0+l)*DI_ + cc4] = sv;
  }
  {
    int row = tid >> 2, q = tid & 3;
    float4 o;
    o.x = pjs[row*21 + 4 + q*4 + 0];
    o.y = pjs[row*21 + 4 + q*4 + 1];
    o.z = pjs[row*21 + 4 + q*4 + 2];
    o.w = pjs[row*21 + 4 + q*4 + 3];
    if (q < 2) *(float4*)&Bm[(size_t)(r0+row)*8 + q*4] = o;
    else       *(float4*)&Cm[(size_t)(r0+row)*8 + (q-2)*4] = o;
  }
}

// ---------------- S1: per-chunk local scan aggregates ----------------
__global__ __launch_bounds__(256) void s1_scan_local(const float* __restrict__ dt,
    const float* __restrict__ xm, const float* __restrict__ Bm, const float* __restrict__ A_log,
    float* __restrict__ aggP, float* __restrict__ aggS) {
  int tid = threadIdx.x;
  int g = tid >> 7; int d = tid & 127;
  int chunkIdx = blockIdx.x*2 + g;
  int b = chunkIdx / NCH_; int ch = chunkIdx % NCH_;
  int l0 = ch * CHUNK_;
  float a[DS_];
  #pragma unroll
  for (int s = 0; s < DS_; ++s) a[s] = -__expf(A_log[d*DS_+s]);
  float P[DS_], S[DS_];
  #pragma unroll
  for (int s = 0; s < DS_; ++s) { P[s] = 1.f; S[s] = 0.f; }
  size_t rbase = (size_t)b*L_ + l0;
  for (int i = 0; i < CHUNK_; ++i) {
    size_t r = rbase + i;
    float dtv = dt[r*DI_ + d];
    float xmv = xm[r*DI_ + d];
    const float4* bp = (const float4*)&Bm[r*8];
    float4 b0 = bp[0], b1 = bp[1];
    float bv[8] = {b0.x,b0.y,b0.z,b0.w,b1.x,b1.y,b1.z,b1.w};
    float dx = dtv * xmv;
    #pragma unroll
    for (int s = 0; s < DS_; ++s) {
      float dA = __expf(dtv * a[s]);
      P[s] *= dA;
      S[s] = dA*S[s] + dx*bv[s];
    }
  }
  size_t o = (((size_t)b*NCH_ + ch)*128 + d)*8;
  float4 p0, p1, s0, s1v;
  p0.x=P[0];p0.y=P[1];p0.z=P[2];p0.w=P[3]; p1.x=P[4];p1.y=P[5];p1.z=P[6];p1.w=P[7];
  s0.x=S[0];s0.y=S[1];s0.z=S[2];s0.w=S[3]; s1v.x=S[4];s1v.y=S[5];s1v.z=S[6];s1v.w=S[7];
  *(float4*)&aggP[o] = p0; *(float4*)&aggP[o+4] = p1;
  *(float4*)&aggS[o] = s0; *(float4*)&aggS[o+4] = s1v;
}

// ---------------- S2: serial combine across chunks ----------------
__global__ __launch_bounds__(256) void s2_scan_chunks(const float* __restrict__ aggP,
    const float* __restrict__ aggS, float* __restrict__ hIn) {
  int gidx = blockIdx.x*256 + threadIdx.x;   // (b, d*8+s)
  int b = gidx >> 10; int rem = gidx & 1023;
  float S = 0.f;
  #pragma unroll 8
  for (int ch = 0; ch < NCH_; ++ch) {
    size_t o = ((size_t)b*NCH_ + ch)*1024 + rem;
    hIn[o] = S;
    S = aggP[o]*S + aggS[o];
  }
}

// ---------------- S3: apply scan + gate ----------------
__global__ __launch_bounds__(256) void s3_scan_apply(const float* __restrict__ dt,
    const float* __restrict__ xm, const float* __restrict__ Bm, const float* __restrict__ Cm,
    const float* __restrict__ z, const float* __restrict__ A_log, const float* __restrict__ Dp,
    const float* __restrict__ hIn, float* __restrict__ y2) {
  int tid = threadIdx.x;
  int g = tid >> 7; int d = tid & 127;
  int chunkIdx = blockIdx.x*2 + g;
  int b = chunkIdx / NCH_; int ch = chunkIdx % NCH_;
  int l0 = ch * CHUNK_;
  float a[DS_];
  #pragma unroll
  for (int s = 0; s < DS_; ++s) a[s] = -__expf(A_log[d*DS_+s]);
  float h[DS_];
  size_t o = (((size_t)b*NCH_ + ch)*128 + d)*8;
  #pragma unroll
  for (int s = 0; s < DS_; ++s) h[s] = hIn[o+s];
  float Dpd = Dp[d];
  size_t rbase = (size_t)b*L_ + l0;
  for (int i = 0; i < CHUNK_; ++i) {
    size_t r = rbase + i;
    float dtv = dt[r*DI_ + d];
    float xmv = xm[r*DI_ + d];
    float zv  = z[r*DI_ + d];
    const float4* bp = (const float4*)&Bm[r*8];
    const float4* cp = (const float4*)&Cm[r*8];
    float4 b0 = bp[0], b1 = bp[1], c0 = cp[0], c1 = cp[1];
    float bv[8] = {b0.x,b0.y,b0.z,b0.w,b1.x,b1.y,b1.z,b1.w};
    float cv[8] = {c0.x,c0.y,c0.z,c0.w,c1.x,c1.y,c1.z,c1.w};
    float dx = dtv * xmv;
    float yv = xmv * Dpd;
    #pragma unroll
    for (int s = 0; s < DS_; ++s) {
      float dA = __expf(dtv * a[s]);
      h[s] = dA*h[s] + dx*bv[s];
      yv += h[s]*cv[s];
    }
    float sg = 1.f / (1.f + __expf(-zv));
    y2[r*DI_ + d] = yv * zv * sg;
  }
}

// ---------------- G2: out_proj GEMM + u residual -> d_out ----------------
__global__ __launch_bounds__(256) void g2_outproj(const float* __restrict__ y2,
    const float* __restrict__ W, const float* __restrict__ u, float* __restrict__ out) {
  __shared__ float at[128][68];
  __shared__ float bt[128][68];
  int tid = threadIdx.x;
  int r0 = blockIdx.x*64;
  for (int idx = tid; idx < 64*32; idx += 256) {
    int row = idx >> 5, c4 = idx & 31;
    float4 v = *(const float4*)&y2[((size_t)(r0+row))*128 + c4*4];
    at[c4*4+0][row] = v.x; at[c4*4+1][row] = v.y; at[c4*4+2][row] = v.z; at[c4*4+3][row] = v.w;
  }
  for (int idx = tid; idx < 128*16; idx += 256) {
    int k = idx >> 4, j4 = idx & 15;
    *(float4*)&bt[k][j4*4] = *(const float4*)&W[(size_t)k*64 + j4*4];
  }
  __syncthreads();
  int ty = tid >> 4, tx = tid & 15;
  float acc[4][4] = {};
  for (int k = 0; k < 128; ++k) {
    float4 av = *(const float4*)&at[k][ty*4];
    float4 bv = *(const float4*)&bt[k][tx*4];
    acc[0][0] += av.x*bv.x; acc[0][1] += av.x*bv.y; acc[0][2] += av.x*bv.z; acc[0][3] += av.x*bv.w;
    acc[1][0] += av.y*bv.x; acc[1][1] += av.y*bv.y; acc[1][2] += av.y*bv.z; acc[1][3] += av.y*bv.w;
    acc[2][0] += av.z*bv.x; acc[2][1] += av.z*bv.y; acc[2][2] += av.z*bv.z; acc[2][3] += av.z*bv.w;
    acc[3][0] += av.w*bv.x; acc[3][1] += av.w*bv.y; acc[3][2] += av.w*bv.z; acc[3][3] += av.w*bv.w;
  }
  #pragma unroll
  for (int i = 0; i < 4; ++i) {
    size_t row = r0 + ty*4 + i;
    int col = tx*4;
    float4 uv = *(const float4*)&u[row*64 + col];
    float4 o;
    o.x = uv.x + acc[i][0]; o.y = uv.y + acc[i][1]; o.z = uv.z + acc[i][2]; o.w = uv.w + acc[i][3];
    *(float4*)&out[row*64 + col] = o;
  }
}

// ---------------- launch ----------------
extern "C" void kernel_launch(void* const* d_in, const int* in_sizes, int n_in,
                              void* d_out, int out_size, void* d_ws, size_t ws_size,
                              hipStream_t stream) {
  const float* x        = (const float*)d_in[0];
  const float* mconv_w  = (const float*)d_in[1];
  const float* mconv_b  = (const float*)d_in[2];
  const float* mWq      = (const float*)d_in[3];
  const float* mMk      = (const float*)d_in[4];
  const float* mMv      = (const float*)d_in[5];
  const float* memWq    = (const float*)d_in[6];
  const float* memM     = (const float*)d_in[7];
  const float* memWo    = (const float*)d_in[8];
  const float* memWt    = (const float*)d_in[9];
  const float* ln_w     = (const float*)d_in[10];
  const float* ln_b     = (const float*)d_in[11];
  const float* in_proj  = (const float*)d_in[12];
  const float* conv1d_w = (const float*)d_in[13];
  const float* conv1d_b = (const float*)d_in[14];
  const float* x_proj   = (const float*)d_in[15];
  const float* dt_w     = (const float*)d_in[16];
  const float* dt_b     = (const float*)d_in[17];
  const float* A_log    = (const float*)d_in[18];
  const float* Dp       = (const float*)d_in[19];
  const float* out_proj = (const float*)d_in[20];
  float* out = (float*)d_out;
  float* ws  = (float*)d_ws;

  float* W1      = ws + 0;
  float* W1m     = ws + 640;
  float* W2m     = ws + 1280;
  float* conv_out= ws + 2048;                  // 1,310,720
  float* memo    = ws + 1312768;               // 4,456,448
  float* u       = ws + 5769216;               // 3,145,728
  float* un      = ws + 8914944;               // 3,145,728
  float* xm_raw  = ws + 12060672;              // 6,291,456 (reused as y2)
  float* z       = ws + 18352128;              // 6,291,456
  float* xm      = ws + 24643584;              // 6,291,456
  float* dt      = ws + 30935040;              // 6,291,456
  float* Bm      = ws + 37226496;               // 393,216
  float* Cm      = ws + 37619712;               // 393,216
  float* aggP    = ws + 38012928;               // 786,432
  float* aggS    = ws + 38799360;               // 786,432
  float* hIn     = ws + 39585792;               // 786,432
  float* y2      = xm_raw;                      // reuse (dead after k5)
  float* conv_raw= un;                          // reuse (dead after k1b; k3 rewrites un)

  hipLaunchKernelGGL(k0_precomp, dim3(1), dim3(64), 0, stream,
                     mWq, mMk, memWq, memM, memWo, W1, W1m, W2m);
  hipLaunchKernelGGL(k1a_conv, dim3(32, 5, 2), dim3(256), 0, stream,
                     x, mconv_w, mconv_b, conv_raw);
  hipLaunchKernelGGL(k1b_att, dim3(80), dim3(256), 0, stream,
                     conv_raw, W1, mMv, conv_out);
  hipLaunchKernelGGL(k2_mem, dim3(272), dim3(256), 0, stream,
                     x, conv_out, W1m, W2m, memo);
  hipLaunchKernelGGL(k3_mix_ln, dim3(1024), dim3(256), 0, stream,
                     x, memo, memWt, ln_w, ln_b, u, un);
  hipLaunchKernelGGL(g1_inproj, dim3(768, 4), dim3(256), 0, stream,
                     un, in_proj, xm_raw, z);
  hipLaunchKernelGGL(k5_conv_proj, dim3(768), dim3(256), 0, stream,
                     xm_raw, conv1d_w, conv1d_b, x_proj, dt_w, dt_b, xm, dt, Bm, Cm);
  hipLaunchKernelGGL(s1_scan_local, dim3(384), dim3(256), 0, stream,
                     dt, xm, Bm, A_log, aggP, aggS);
  hipLaunchKernelGGL(s2_scan_chunks, dim3(8), dim3(256), 0, stream,
                     aggP, aggS, hIn);
  hipLaunchKernelGGL(s3_scan_apply, dim3(384), dim3(256), 0, stream,
                     dt, xm, Bm, Cm, z, A_log, Dp, hIn, y2);
  hipLaunchKernelGGL(g2_outproj, dim3(768), dim3(256), 0, stream,
                     y2, out_proj, u, out);
}

// Round 3
// 240.212 us; speedup vs baseline: 1.3561x; 1.1365x over previous
//
#include <hip/hip_runtime.h>
#include <math.h>

#define B_  2
#define T_  12
#define N_  2048
#define D_  64
#define DI_ 128
#define DS_ 8
#define NM_ 10
#define CK_ 3
#define CS_ 2
#define TC_ 5
#define TT_ 17
#define L_  (T_*N_)        // 24576
#define CHUNK_ 64
#define NCH_ (L_/CHUNK_)   // 384

// ---------------- K0: fold small weight products ----------------
__global__ void k0_precomp(const float* __restrict__ msam_Wq, const float* __restrict__ msam_Mk,
                           const float* __restrict__ mem_Wq, const float* __restrict__ mem_M,
                           const float* __restrict__ mem_Wo,
                           float* __restrict__ W1, float* __restrict__ W1m, float* __restrict__ W2m) {
  int d = threadIdx.x;
  if (d >= 64) return;
  for (int m = 0; m < NM_; ++m) {
    float a = 0.f;
    for (int j = 0; j < 4; ++j) a += msam_Wq[d*4+j] * msam_Mk[m*4+j];
    W1[d*10+m] = a;
    float b = 0.f;
    for (int k = 0; k < 64; ++k) b += mem_Wq[d*64+k] * mem_M[m*64+k];
    W1m[d*10+m] = b;
    float c = 0.f;
    for (int k = 0; k < 64; ++k) c += mem_M[m*64+k] * mem_Wo[k*64+d];
    W2m[m*64+d] = c;
  }
}

// ---------------- K1a: msam conv as tiled fp32 GEMM ----------------
__global__ __launch_bounds__(256) void k1a_conv(const float* __restrict__ x,
    const float* __restrict__ cw, const float* __restrict__ cb,
    float* __restrict__ conv_raw) {
  __shared__ float ats[64*65];
  __shared__ float bts[192*64];
  int tid = threadIdx.x;
  int n0 = blockIdx.x * 64;
  int tc = blockIdx.y;
  int b  = blockIdx.z;
  for (int i = tid; i < 3072; i += 256)
    ((float4*)bts)[i] = ((const float4*)cw)[i];
  int ty = tid >> 4, tx = tid & 15;
  float acc[4][4] = {};
  for (int kk = 0; kk < 3; ++kk) {
    __syncthreads();
    const float* xs = x + (((size_t)b*T_ + (2*tc+kk))*N_ + n0)*64;
    for (int i = tid; i < 1024; i += 256) {
      int r = i >> 4, c = (i & 15) * 4;
      float4 v = ((const float4*)xs)[i];
      ats[r*65+c+0]=v.x; ats[r*65+c+1]=v.y; ats[r*65+c+2]=v.z; ats[r*65+c+3]=v.w;
    }
    __syncthreads();
    for (int k = 0; k < 64; ++k) {
      float a0 = ats[(ty*4+0)*65 + k];
      float a1 = ats[(ty*4+1)*65 + k];
      float a2 = ats[(ty*4+2)*65 + k];
      float a3 = ats[(ty*4+3)*65 + k];
      float4 bv = *(float4*)&bts[(kk*64+k)*64 + tx*4];
      acc[0][0]+=a0*bv.x; acc[0][1]+=a0*bv.y; acc[0][2]+=a0*bv.z; acc[0][3]+=a0*bv.w;
      acc[1][0]+=a1*bv.x; acc[1][1]+=a1*bv.y; acc[1][2]+=a1*bv.z; acc[1][3]+=a1*bv.w;
      acc[2][0]+=a2*bv.x; acc[2][1]+=a2*bv.y; acc[2][2]+=a2*bv.z; acc[2][3]+=a2*bv.w;
      acc[3][0]+=a3*bv.x; acc[3][1]+=a3*bv.y; acc[3][2]+=a3*bv.z; acc[3][3]+=a3*bv.w;
    }
  }
  float4 cbv = *(const float4*)&cb[tx*4];
  size_t rowbase = ((size_t)b*TC_ + tc)*N_ + n0;
  #pragma unroll
  for (int i = 0; i < 4; ++i) {
    float4 o;
    o.x = acc[i][0]+cbv.x; o.y = acc[i][1]+cbv.y; o.z = acc[i][2]+cbv.z; o.w = acc[i][3]+cbv.w;
    *(float4*)&conv_raw[(rowbase + ty*4+i)*64 + tx*4] = o;
  }
}

// ---------------- K1b: msam attention ----------------
__global__ __launch_bounds__(256) void k1b_att(const float* __restrict__ conv_raw,
    const float* __restrict__ W1, const float* __restrict__ Mv,
    float* __restrict__ conv_out) {
  __shared__ float xt[4][64*66];
  __shared__ float w1T[10*66];
  int tid = threadIdx.x;
  for (int i = tid; i < 640; i += 256) {
    int c = i / 10, m = i % 10;
    w1T[m*66 + c] = W1[i];
  }
  int w = tid >> 6, lane = tid & 63;
  int R0 = blockIdx.x*256 + w*64;
  const float* src = conv_raw + (size_t)R0*64;
  float* xtw = xt[w];
  for (int it = 0; it < 16; ++it) {
    int flat = it*256 + lane*4;
    int r = flat >> 6, c = flat & 63;
    float4 v = *(const float4*)&src[(size_t)r*64 + c];
    xtw[r*66+c+0]=v.x; xtw[r*66+c+1]=v.y; xtw[r*66+c+2]=v.z; xtw[r*66+c+3]=v.w;
  }
  float w2r[10];
  #pragma unroll
  for (int j = 0; j < 10; ++j) w2r[j] = Mv[j*64 + lane];
  __syncthreads();
  float p[10] = {};
  #pragma unroll 4
  for (int c2 = 0; c2 < 32; ++c2) {
    float2 v = *(float2*)&xtw[lane*66 + c2*2];
    #pragma unroll
    for (int j = 0; j < 10; ++j) {
      float2 wv = *(float2*)&w1T[j*66 + c2*2];
      p[j] += v.x*wv.x + v.y*wv.y;
    }
  }
  float m = p[0];
  #pragma unroll
  for (int j = 1; j < 10; ++j) m = fmaxf(m, p[j]);
  float att[10]; float ssum = 0.f;
  #pragma unroll
  for (int j = 0; j < 10; ++j) { att[j] = __expf(p[j]-m); ssum += att[j]; }
  float inv = 1.f/ssum;
  #pragma unroll
  for (int j = 0; j < 10; ++j) att[j] *= inv;
  float* dst = conv_out + (size_t)R0*64;
  for (int r = 0; r < 64; ++r) {
    float o = xtw[r*66 + lane];
    #pragma unroll
    for (int j = 0; j < 10; ++j) o += __shfl(att[j], r, 64) * w2r[j];
    dst[(size_t)r*64 + lane] = o;
  }
}

// ---------------- K2: memory attention ----------------
__global__ __launch_bounds__(256) void k2_mem(const float* __restrict__ x,
    const float* __restrict__ conv_out, const float* __restrict__ W1m,
    const float* __restrict__ W2m, float* __restrict__ memo) {
  __shared__ float xt[4][64*66];
  __shared__ float w1T[10*66];
  int tid = threadIdx.x;
  for (int i = tid; i < 640; i += 256) {
    int c = i / 10, m = i % 10;
    w1T[m*66 + c] = W1m[i];
  }
  int w = tid >> 6, lane = tid & 63;
  int R0 = blockIdx.x*256 + w*64;
  int n0 = R0 & (N_-1);
  int sb = R0 >> 11;
  int s  = sb % TT_;
  int b  = sb / TT_;
  const float* src = (s < T_) ? (x + (((size_t)b*T_ + s)*N_ + n0)*64)
                              : (conv_out + (((size_t)b*TC_ + (s-T_))*N_ + n0)*64);
  float* xtw = xt[w];
  for (int it = 0; it < 16; ++it) {
    int flat = it*256 + lane*4;
    int r = flat >> 6, c = flat & 63;
    float4 v = *(const float4*)&src[(size_t)r*64 + c];
    xtw[r*66+c+0]=v.x; xtw[r*66+c+1]=v.y; xtw[r*66+c+2]=v.z; xtw[r*66+c+3]=v.w;
  }
  float w2r[10];
  #pragma unroll
  for (int j = 0; j < 10; ++j) w2r[j] = W2m[j*64 + lane];
  __syncthreads();
  float p[10] = {};
  #pragma unroll 4
  for (int c2 = 0; c2 < 32; ++c2) {
    float2 v = *(float2*)&xtw[lane*66 + c2*2];
    #pragma unroll
    for (int j = 0; j < 10; ++j) {
      float2 wv = *(float2*)&w1T[j*66 + c2*2];
      p[j] += v.x*wv.x + v.y*wv.y;
    }
  }
  float m = p[0];
  #pragma unroll
  for (int j = 1; j < 10; ++j) m = fmaxf(m, p[j]);
  float att[10]; float ssum = 0.f;
  #pragma unroll
  for (int j = 0; j < 10; ++j) { att[j] = __expf(p[j]-m); ssum += att[j]; }
  float inv = 1.f/ssum;
  #pragma unroll
  for (int j = 0; j < 10; ++j) att[j] *= inv;
  float* dst = memo + (((size_t)b*TT_ + s)*N_ + n0)*64;
  for (int r = 0; r < 64; ++r) {
    float o = 0.f;
    #pragma unroll
    for (int j = 0; j < 10; ++j) o += __shfl(att[j], r, 64) * w2r[j];
    dst[(size_t)r*64 + lane] = o;
  }
}

// ---------------- K3: time-mix einsum + residual + LayerNorm ----------------
__global__ __launch_bounds__(256) void k3_mix_ln(const float* __restrict__ x,
    const float* __restrict__ memo, const float* __restrict__ Wt,
    const float* __restrict__ ln_w, const float* __restrict__ ln_b,
    float* __restrict__ u, float* __restrict__ un) {
  __shared__ float wt[T_*TT_];
  int tid = threadIdx.x;
  for (int i = tid; i < T_*TT_; i += 256) wt[i] = Wt[i];
  __syncthreads();
  int wv = blockIdx.x*4 + (tid >> 6);
  int lane = tid & 63;
  int b = wv / N_; int n = wv % N_;
  float ms[TT_];
  #pragma unroll
  for (int s = 0; s < TT_; ++s)
    ms[s] = memo[(((size_t)b*TT_+s)*N_+n)*64 + lane];
  float lw = ln_w[lane], lb = ln_b[lane];
  for (int t = 0; t < T_; ++t) {
    float acc = x[(((size_t)b*T_+t)*N_+n)*64 + lane];
    #pragma unroll
    for (int s = 0; s < TT_; ++s) acc += wt[t*TT_+s] * ms[s];
    size_t ro = ((size_t)b*L_ + (size_t)t*N_ + n)*64 + lane;
    u[ro] = acc;
    float s1 = acc, s2 = acc*acc;
    #pragma unroll
    for (int m = 1; m < 64; m <<= 1) { s1 += __shfl_xor(s1, m, 64); s2 += __shfl_xor(s2, m, 64); }
    float mu = s1 * (1.f/64.f);
    float var = s2 * (1.f/64.f) - mu*mu;
    float iv = rsqrtf(var + 1e-5f);
    un[ro] = (acc - mu) * iv * lw + lb;
  }
}

// ---------------- F1: in_proj GEMM + conv1d + silu + x_proj + dt + chunk-scan agg ----------------
// per 64-row chunk; buf1 = unT[64][68] -> xpT[20][132]+pjs[64][24]; buf2 = W stage -> xv[64][132]
__global__ __launch_bounds__(256) void f1_chunk(const float* __restrict__ un,
    const float* __restrict__ W, const float* __restrict__ cw, const float* __restrict__ cb,
    const float* __restrict__ xpw, const float* __restrict__ dtw, const float* __restrict__ dtb,
    const float* __restrict__ A_log,
    float* __restrict__ xm, float* __restrict__ z, float* __restrict__ dt,
    float* __restrict__ Bm, float* __restrict__ Cm,
    float* __restrict__ aggP, float* __restrict__ aggS) {
  __shared__ float buf1[64*68];     // 17.0 KB
  __shared__ float buf2[64*132];    // 33.8 KB
  int tid = threadIdx.x;
  int cid = blockIdx.x;
  int b = cid / NCH_;
  int l0 = (cid % NCH_) * 64;
  size_t rbase = (size_t)b*L_ + l0;
  const float* unb = un + (size_t)b*L_*64;
  // phase 0: load unT (67 rows, halo l0-3..l0-1 zero at seq start) + stage W_x into buf2
  for (int i = tid; i < 67*16; i += 256) {
    int rr = i >> 4, k4 = i & 15;
    int gl = l0 - 3 + rr;
    float4 v = make_float4(0.f,0.f,0.f,0.f);
    if (gl >= 0) v = *(const float4*)&unb[(size_t)gl*64 + k4*4];
    buf1[(k4*4+0)*68 + rr] = v.x;
    buf1[(k4*4+1)*68 + rr] = v.y;
    buf1[(k4*4+2)*68 + rr] = v.z;
    buf1[(k4*4+3)*68 + rr] = v.w;
  }
  for (int i = tid; i < 2048; i += 256) {
    int k = i >> 5, c4i = i & 31;
    *(float4*)&buf2[k*132 + c4i*4] = *(const float4*)&W[(size_t)k*256 + c4i*4];
  }
  __syncthreads();
  int c4 = tid & 31, rgrp = tid >> 5;   // c = c4*4; output rows rgrp*8..rgrp*8+7
  // phase 1: xm_raw GEMM, 11-row strip (3-row halo in-registers)
  float acc[11][4] = {};
  for (int k = 0; k < 64; ++k) {
    float4 bv = *(float4*)&buf2[k*132 + c4*4];
    #pragma unroll
    for (int j = 0; j < 11; ++j) {
      float a = buf1[k*68 + rgrp*8 + j];
      acc[j][0] += a*bv.x; acc[j][1] += a*bv.y; acc[j][2] += a*bv.z; acc[j][3] += a*bv.w;
    }
  }
  // conv + silu in registers
  float4 w0 = *(const float4*)&cw[0*DI_ + c4*4];
  float4 w1 = *(const float4*)&cw[1*DI_ + c4*4];
  float4 w2 = *(const float4*)&cw[2*DI_ + c4*4];
  float4 w3 = *(const float4*)&cw[3*DI_ + c4*4];
  float4 cbv = *(const float4*)&cb[c4*4];
  float sil[8][4];
  #pragma unroll
  for (int j = 0; j < 8; ++j) {
    float a0 = cbv.x + acc[j][0]*w0.x + acc[j+1][0]*w1.x + acc[j+2][0]*w2.x + acc[j+3][0]*w3.x;
    float a1 = cbv.y + acc[j][1]*w0.y + acc[j+1][1]*w1.y + acc[j+2][1]*w2.y + acc[j+3][1]*w3.y;
    float a2 = cbv.z + acc[j][2]*w0.z + acc[j+1][2]*w1.z + acc[j+2][2]*w2.z + acc[j+3][2]*w3.z;
    float a3 = cbv.w + acc[j][3]*w0.w + acc[j+1][3]*w1.w + acc[j+2][3]*w2.w + acc[j+3][3]*w3.w;
    sil[j][0] = a0 / (1.f + __expf(-a0));
    sil[j][1] = a1 / (1.f + __expf(-a1));
    sil[j][2] = a2 / (1.f + __expf(-a2));
    sil[j][3] = a3 / (1.f + __expf(-a3));
  }
  __syncthreads();
  // phase 1b: stage W_z, z GEMM (rows without halo: unT rr = 3 + local row)
  for (int i = tid; i < 2048; i += 256) {
    int k = i >> 5, c4i = i & 31;
    *(float4*)&buf2[k*132 + c4i*4] = *(const float4*)&W[(size_t)k*256 + 128 + c4i*4];
  }
  __syncthreads();
  {
    float acc2[8][4] = {};
    for (int k = 0; k < 64; ++k) {
      float4 bv = *(float4*)&buf2[k*132 + c4*4];
      #pragma unroll
      for (int j = 0; j < 8; ++j) {
        float a = buf1[k*68 + rgrp*8 + 3 + j];
        acc2[j][0] += a*bv.x; acc2[j][1] += a*bv.y; acc2[j][2] += a*bv.z; acc2[j][3] += a*bv.w;
      }
    }
    #pragma unroll
    for (int j = 0; j < 8; ++j) {
      float4 o; o.x=acc2[j][0]; o.y=acc2[j][1]; o.z=acc2[j][2]; o.w=acc2[j][3];
      *(float4*)&z[(rbase + rgrp*8 + j)*DI_ + c4*4] = o;
    }
  }
  __syncthreads();
  // phase 2: store xv into buf2, write xm to global, load xpT into buf1
  float* xv = buf2;                   // [64][132]
  #pragma unroll
  for (int j = 0; j < 8; ++j) {
    float4 o; o.x=sil[j][0]; o.y=sil[j][1]; o.z=sil[j][2]; o.w=sil[j][3];
    *(float4*)&xv[(rgrp*8+j)*132 + c4*4] = o;
    *(float4*)&xm[(rbase + rgrp*8 + j)*DI_ + c4*4] = o;
  }
  float* xpT = buf1;                  // [20][132]
  float* pjs = buf1 + 2688;           // [64][24]
  for (int i = tid; i < 2560; i += 256) {
    int c = i / 20, j = i % 20;
    xpT[j*132 + c] = xpw[i];
  }
  __syncthreads();
  // phase 3: x_proj mini-GEMM (row per thread-quad)
  {
    int row = tid >> 2, q = tid & 3, j0 = q*5;
    float a5[5] = {0,0,0,0,0};
    for (int k4 = 0; k4 < 32; ++k4) {
      float4 a4 = *(float4*)&xv[row*132 + k4*4];
      #pragma unroll
      for (int jj = 0; jj < 5; ++jj) {
        float4 b4 = *(float4*)&xpT[(j0+jj)*132 + k4*4];
        a5[jj] += a4.x*b4.x + a4.y*b4.y + a4.z*b4.z + a4.w*b4.w;
      }
    }
    #pragma unroll
    for (int jj = 0; jj < 5; ++jj) pjs[row*24 + j0+jj] = a5[jj];
  }
  __syncthreads();
  // phase 4: dt epilogue (store dt), B/C store
  {
    float4 dw0 = *(const float4*)&dtw[0*DI_ + c4*4];
    float4 dw1 = *(const float4*)&dtw[1*DI_ + c4*4];
    float4 dw2 = *(const float4*)&dtw[2*DI_ + c4*4];
    float4 dw3 = *(const float4*)&dtw[3*DI_ + c4*4];
    float4 dbv = *(const float4*)&dtb[c4*4];
    #pragma unroll
    for (int j = 0; j < 8; ++j) {
      int row = rgrp*8 + j;
      float p0 = pjs[row*24+0], p1 = pjs[row*24+1], p2 = pjs[row*24+2], p3 = pjs[row*24+3];
      float a0 = dbv.x + p0*dw0.x + p1*dw1.x + p2*dw2.x + p3*dw3.x;
      float a1 = dbv.y + p0*dw0.y + p1*dw1.y + p2*dw2.y + p3*dw3.y;
      float a2 = dbv.z + p0*dw0.z + p1*dw1.z + p2*dw2.z + p3*dw3.z;
      float a3 = dbv.w + p0*dw0.w + p1*dw1.w + p2*dw2.w + p3*dw3.w;
      float4 o;
      o.x = (a0 > 15.f) ? a0 : __logf(1.f + __expf(a0));
      o.y = (a1 > 15.f) ? a1 : __logf(1.f + __expf(a1));
      o.z = (a2 > 15.f) ? a2 : __logf(1.f + __expf(a2));
      o.w = (a3 > 15.f) ? a3 : __logf(1.f + __expf(a3));
      *(float4*)&dt[(rbase + row)*DI_ + c4*4] = o;
    }
    int row = tid >> 2, q = tid & 3;
    float4 o;
    o.x = pjs[row*24 + 4 + q*4 + 0];
    o.y = pjs[row*24 + 4 + q*4 + 1];
    o.z = pjs[row*24 + 4 + q*4 + 2];
    o.w = pjs[row*24 + 4 + q*4 + 3];
    if (q < 2) *(float4*)&Bm[(rbase+row)*8 + q*4] = o;
    else       *(float4*)&Cm[(rbase+row)*8 + (q-2)*4] = o;
  }
  // phase 5: chunk-local scan aggregates (s1 fused); thread = (d, s-quad)
  {
    int d = tid & 127, q = tid >> 7;      // q in {0,1}: s = q*4..q*4+3
    float4 av = *(const float4*)&A_log[d*8 + q*4];
    float a0 = -__expf(av.x), a1 = -__expf(av.y), a2 = -__expf(av.z), a3 = -__expf(av.w);
    float dtw0 = dtw[0*DI_+d], dtw1 = dtw[1*DI_+d], dtw2 = dtw[2*DI_+d], dtw3 = dtw[3*DI_+d];
    float dtbd = dtb[d];
    float P0=1.f,P1=1.f,P2=1.f,P3=1.f, S0=0.f,S1=0.f,S2=0.f,S3=0.f;
    for (int r = 0; r < 64; ++r) {
      float p0 = pjs[r*24+0], p1 = pjs[r*24+1], p2 = pjs[r*24+2], p3 = pjs[r*24+3];
      float aa = dtbd + p0*dtw0 + p1*dtw1 + p2*dtw2 + p3*dtw3;
      float dtv = (aa > 15.f) ? aa : __logf(1.f + __expf(aa));
      float dx = dtv * xv[r*132 + d];
      float b0 = pjs[r*24 + 4 + q*4 + 0];
      float b1 = pjs[r*24 + 4 + q*4 + 1];
      float b2 = pjs[r*24 + 4 + q*4 + 2];
      float b3 = pjs[r*24 + 4 + q*4 + 3];
      float e0 = __expf(dtv*a0), e1 = __expf(dtv*a1), e2 = __expf(dtv*a2), e3 = __expf(dtv*a3);
      P0*=e0; P1*=e1; P2*=e2; P3*=e3;
      S0 = e0*S0 + dx*b0; S1 = e1*S1 + dx*b1; S2 = e2*S2 + dx*b2; S3 = e3*S3 + dx*b3;
    }
    size_t o = (((size_t)cid)*128 + d)*8 + q*4;
    float4 pv; pv.x=P0; pv.y=P1; pv.z=P2; pv.w=P3;
    float4 sv; sv.x=S0; sv.y=S1; sv.z=S2; sv.w=S3;
    *(float4*)&aggP[o] = pv;
    *(float4*)&aggS[o] = sv;
  }
}

// ---------------- S2: serial combine across chunks ----------------
__global__ __launch_bounds__(256) void s2_scan_chunks(const float* __restrict__ aggP,
    const float* __restrict__ aggS, float* __restrict__ hIn) {
  int gidx = blockIdx.x*256 + threadIdx.x;   // (b, d*8+s)
  int b = gidx >> 10; int rem = gidx & 1023;
  float S = 0.f;
  #pragma unroll 8
  for (int ch = 0; ch < NCH_; ++ch) {
    size_t o = ((size_t)b*NCH_ + ch)*1024 + rem;
    hIn[o] = S;
    S = aggP[o]*S + aggS[o];
  }
}

// ---------------- F3: scan apply + gate + out_proj GEMM + residual ----------------
__global__ __launch_bounds__(256) void f3_scan_out(const float* __restrict__ dt,
    const float* __restrict__ xm, const float* __restrict__ z,
    const float* __restrict__ Bm, const float* __restrict__ Cm,
    const float* __restrict__ hIn, const float* __restrict__ A_log,
    const float* __restrict__ Dp, const float* __restrict__ Wo,
    const float* __restrict__ u, float* __restrict__ out) {
  __shared__ float y2t[64*132];   // 33.8 KB
  __shared__ float bc[64*16];     // 4 KB: [row][0..7]=B, [8..15]=C
  int tid = threadIdx.x;
  int cid = blockIdx.x;
  int b = cid / NCH_;
  int l0 = (cid % NCH_) * 64;
  size_t rbase = (size_t)b*L_ + l0;
  {
    int row = tid >> 2, q = tid & 3;
    float4 v = (q < 2) ? *(const float4*)&Bm[(rbase+row)*8 + q*4]
                       : *(const float4*)&Cm[(rbase+row)*8 + (q-2)*4];
    *(float4*)&bc[row*16 + q*4] = v;
  }
  __syncthreads();
  if (tid < 128) {
    int d = tid;
    float a[DS_], h[DS_];
    #pragma unroll
    for (int s = 0; s < DS_; ++s) a[s] = -__expf(A_log[d*8+s]);
    size_t o = (((size_t)cid)*128 + d)*8;
    #pragma unroll
    for (int s = 0; s < DS_; ++s) h[s] = hIn[o+s];
    float Dpd = Dp[d];
    for (int r = 0; r < 64; ++r) {
      size_t rr = rbase + r;
      float dtv = dt[rr*DI_ + d];
      float xmv = xm[rr*DI_ + d];
      float zv  = z[rr*DI_ + d];
      float dx = dtv * xmv;
      float yv = xmv * Dpd;
      #pragma unroll
      for (int s = 0; s < DS_; ++s) {
        float dA = __expf(dtv * a[s]);
        h[s] = dA*h[s] + dx*bc[r*16 + s];
        yv += h[s]*bc[r*16 + 8 + s];
      }
      float sg = 1.f / (1.f + __expf(-zv));
      y2t[r*132 + d] = yv * zv * sg;
    }
  }
  __syncthreads();
  // GEMM: out[64x64] = y2t[64x128] @ Wo[128x64] + u
  int tx = tid & 15, ty = tid >> 4;
  int col = tx*4;
  float acc[4][4] = {};
  for (int k = 0; k < 128; ++k) {
    float4 bv = *(const float4*)&Wo[(size_t)k*64 + col];
    #pragma unroll
    for (int i = 0; i < 4; ++i) {
      float a = y2t[(ty*4+i)*132 + k];
      acc[i][0] += a*bv.x; acc[i][1] += a*bv.y; acc[i][2] += a*bv.z; acc[i][3] += a*bv.w;
    }
  }
  #pragma unroll
  for (int i = 0; i < 4; ++i) {
    size_t row = rbase + ty*4 + i;
    float4 uv = *(const float4*)&u[row*64 + col];
    float4 o;
    o.x = uv.x + acc[i][0]; o.y = uv.y + acc[i][1]; o.z = uv.z + acc[i][2]; o.w = uv.w + acc[i][3];
    *(float4*)&out[row*64 + col] = o;
  }
}

// ---------------- launch ----------------
extern "C" void kernel_launch(void* const* d_in, const int* in_sizes, int n_in,
                              void* d_out, int out_size, void* d_ws, size_t ws_size,
                              hipStream_t stream) {
  const float* x        = (const float*)d_in[0];
  const float* mconv_w  = (const float*)d_in[1];
  const float* mconv_b  = (const float*)d_in[2];
  const float* mWq      = (const float*)d_in[3];
  const float* mMk      = (const float*)d_in[4];
  const float* mMv      = (const float*)d_in[5];
  const float* memWq    = (const float*)d_in[6];
  const float* memM     = (const float*)d_in[7];
  const float* memWo    = (const float*)d_in[8];
  const float* memWt    = (const float*)d_in[9];
  const float* ln_w     = (const float*)d_in[10];
  const float* ln_b     = (const float*)d_in[11];
  const float* in_proj  = (const float*)d_in[12];
  const float* conv1d_w = (const float*)d_in[13];
  const float* conv1d_b = (const float*)d_in[14];
  const float* x_proj   = (const float*)d_in[15];
  const float* dt_w     = (const float*)d_in[16];
  const float* dt_b     = (const float*)d_in[17];
  const float* A_log    = (const float*)d_in[18];
  const float* Dp       = (const float*)d_in[19];
  const float* out_proj = (const float*)d_in[20];
  float* out = (float*)d_out;
  float* ws  = (float*)d_ws;

  float* W1      = ws + 0;
  float* W1m     = ws + 640;
  float* W2m     = ws + 1280;
  float* conv_out= ws + 2048;
  float* memo    = ws + 1312768;
  float* u       = ws + 5769216;
  float* un      = ws + 8914944;
  float* z       = ws + 18352128;
  float* xm      = ws + 24643584;
  float* dt      = ws + 30935040;
  float* Bm      = ws + 37226496;
  float* Cm      = ws + 37619712;
  float* aggP    = ws + 38012928;
  float* aggS    = ws + 38799360;
  float* hIn     = ws + 39585792;
  float* conv_raw= un;                       // dead after k1b; k3 rewrites un

  hipLaunchKernelGGL(k0_precomp, dim3(1), dim3(64), 0, stream,
                     mWq, mMk, memWq, memM, memWo, W1, W1m, W2m);
  hipLaunchKernelGGL(k1a_conv, dim3(32, 5, 2), dim3(256), 0, stream,
                     x, mconv_w, mconv_b, conv_raw);
  hipLaunchKernelGGL(k1b_att, dim3(80), dim3(256), 0, stream,
                     conv_raw, W1, mMv, conv_out);
  hipLaunchKernelGGL(k2_mem, dim3(272), dim3(256), 0, stream,
                     x, conv_out, W1m, W2m, memo);
  hipLaunchKernelGGL(k3_mix_ln, dim3(1024), dim3(256), 0, stream,
                     x, memo, memWt, ln_w, ln_b, u, un);
  hipLaunchKernelGGL(f1_chunk, dim3(768), dim3(256), 0, stream,
                     un, in_proj, conv1d_w, conv1d_b, x_proj, dt_w, dt_b, A_log,
                     xm, z, dt, Bm, Cm, aggP, aggS);
  hipLaunchKernelGGL(s2_scan_chunks, dim3(8), dim3(256), 0, stream,
                     aggP, aggS, hIn);
  hipLaunchKernelGGL(f3_scan_out, dim3(768), dim3(256), 0, stream,
                     dt, xm, z, Bm, Cm, hIn, A_log, Dp, out_proj, u, out);
}

// Round 5
// 228.675 us; speedup vs baseline: 1.4245x; 1.0504x over previous
//
#include <hip/hip_runtime.h>
#include <math.h>

#define B_  2
#define T_  12
#define N_  2048
#define D_  64
#define DI_ 128
#define DS_ 8
#define NM_ 10
#define CK_ 3
#define CS_ 2
#define TC_ 5
#define TT_ 17
#define L_  (T_*N_)        // 24576
#define CHUNK_ 64
#define NCH_ (L_/CHUNK_)   // 384

// ---------------- K0: fold small weight products ----------------
__global__ void k0_precomp(const float* __restrict__ msam_Wq, const float* __restrict__ msam_Mk,
                           const float* __restrict__ mem_Wq, const float* __restrict__ mem_M,
                           const float* __restrict__ mem_Wo,
                           float* __restrict__ W1, float* __restrict__ W1m, float* __restrict__ W2m) {
  int d = threadIdx.x;
  if (d >= 64) return;
  for (int m = 0; m < NM_; ++m) {
    float a = 0.f;
    for (int j = 0; j < 4; ++j) a += msam_Wq[d*4+j] * msam_Mk[m*4+j];
    W1[d*10+m] = a;
    float b = 0.f;
    for (int k = 0; k < 64; ++k) b += mem_Wq[d*64+k] * mem_M[m*64+k];
    W1m[d*10+m] = b;
    float c = 0.f;
    for (int k = 0; k < 64; ++k) c += mem_M[m*64+k] * mem_Wo[k*64+d];
    W2m[m*64+d] = c;
  }
}

// ---------------- K1a: msam conv as tiled fp32 GEMM ----------------
__global__ __launch_bounds__(256) void k1a_conv(const float* __restrict__ x,
    const float* __restrict__ cw, const float* __restrict__ cb,
    float* __restrict__ conv_raw) {
  __shared__ float ats[64*65];
  __shared__ float bts[192*64];
  int tid = threadIdx.x;
  int n0 = blockIdx.x * 64;
  int tc = blockIdx.y;
  int b  = blockIdx.z;
  for (int i = tid; i < 3072; i += 256)
    ((float4*)bts)[i] = ((const float4*)cw)[i];
  int ty = tid >> 4, tx = tid & 15;
  float acc[4][4] = {};
  for (int kk = 0; kk < 3; ++kk) {
    __syncthreads();
    const float* xs = x + (((size_t)b*T_ + (2*tc+kk))*N_ + n0)*64;
    for (int i = tid; i < 1024; i += 256) {
      int r = i >> 4, c = (i & 15) * 4;
      float4 v = ((const float4*)xs)[i];
      ats[r*65+c+0]=v.x; ats[r*65+c+1]=v.y; ats[r*65+c+2]=v.z; ats[r*65+c+3]=v.w;
    }
    __syncthreads();
    for (int k = 0; k < 64; ++k) {
      float a0 = ats[(ty*4+0)*65 + k];
      float a1 = ats[(ty*4+1)*65 + k];
      float a2 = ats[(ty*4+2)*65 + k];
      float a3 = ats[(ty*4+3)*65 + k];
      float4 bv = *(float4*)&bts[(kk*64+k)*64 + tx*4];
      acc[0][0]+=a0*bv.x; acc[0][1]+=a0*bv.y; acc[0][2]+=a0*bv.z; acc[0][3]+=a0*bv.w;
      acc[1][0]+=a1*bv.x; acc[1][1]+=a1*bv.y; acc[1][2]+=a1*bv.z; acc[1][3]+=a1*bv.w;
      acc[2][0]+=a2*bv.x; acc[2][1]+=a2*bv.y; acc[2][2]+=a2*bv.z; acc[2][3]+=a2*bv.w;
      acc[3][0]+=a3*bv.x; acc[3][1]+=a3*bv.y; acc[3][2]+=a3*bv.z; acc[3][3]+=a3*bv.w;
    }
  }
  float4 cbv = *(const float4*)&cb[tx*4];
  size_t rowbase = ((size_t)b*TC_ + tc)*N_ + n0;
  #pragma unroll
  for (int i = 0; i < 4; ++i) {
    float4 o;
    o.x = acc[i][0]+cbv.x; o.y = acc[i][1]+cbv.y; o.z = acc[i][2]+cbv.z; o.w = acc[i][3]+cbv.w;
    *(float4*)&conv_raw[(rowbase + ty*4+i)*64 + tx*4] = o;
  }
}

// ---------------- K2M: merged msam attention + memory attention ----------------
__global__ __launch_bounds__(256) void k2m(const float* __restrict__ x,
    const float* __restrict__ conv_raw,
    const float* __restrict__ W1s, const float* __restrict__ Mv,
    const float* __restrict__ W1m, const float* __restrict__ W2m,
    float* __restrict__ memo) {
  __shared__ float xt[4][64*68];
  __shared__ float w1sT[640], w1mT[640], MvS[640], W2S[640];
  int tid = threadIdx.x;
  for (int i = tid; i < 640; i += 256) {
    int c = i / 10, m = i % 10;
    w1sT[m*64 + c] = W1s[i];
    w1mT[m*64 + c] = W1m[i];
    MvS[i] = Mv[i];
    W2S[i] = W2m[i];
  }
  int w = tid >> 6, lane = tid & 63;
  int R0 = blockIdx.x*256 + w*64;
  int n0 = R0 & (N_-1);
  int sb = R0 >> 11;
  int s  = sb % TT_;
  int b  = sb / TT_;
  const float* src = (s < T_) ? (x + (((size_t)b*T_ + s)*N_ + n0)*64)
                              : (conv_raw + (((size_t)b*TC_ + (s-T_))*N_ + n0)*64);
  float* xtw = xt[w];
  for (int it = 0; it < 16; ++it) {
    int flat = it*256 + lane*4;
    int r = flat >> 6, c = flat & 63;
    *(float4*)&xtw[r*68 + c] = *(const float4*)&src[(size_t)r*64 + c];
  }
  __syncthreads();
  if (s >= T_) {
    // msam attention applied in-LDS
    float p[10] = {};
    #pragma unroll
    for (int c4 = 0; c4 < 16; ++c4) {
      float4 v = *(float4*)&xtw[lane*68 + c4*4];
      #pragma unroll
      for (int j = 0; j < 10; ++j) {
        float4 wv = *(float4*)&w1sT[j*64 + c4*4];
        p[j] += v.x*wv.x + v.y*wv.y + v.z*wv.z + v.w*wv.w;
      }
    }
    float m = p[0];
    #pragma unroll
    for (int j = 1; j < 10; ++j) m = fmaxf(m, p[j]);
    float att[10]; float ssum = 0.f;
    #pragma unroll
    for (int j = 0; j < 10; ++j) { att[j] = __expf(p[j]-m); ssum += att[j]; }
    float inv = 1.f/ssum;
    #pragma unroll
    for (int j = 0; j < 10; ++j) att[j] *= inv;
    float mvr[10];
    #pragma unroll
    for (int j = 0; j < 10; ++j) mvr[j] = MvS[j*64 + lane];
    for (int r = 0; r < 64; ++r) {
      float add = 0.f;
      #pragma unroll
      for (int j = 0; j < 10; ++j) add += __shfl(att[j], r, 64) * mvr[j];
      xtw[r*68 + lane] += add;
    }
  }
  __syncthreads();
  // memory attention
  float p[10] = {};
  #pragma unroll
  for (int c4 = 0; c4 < 16; ++c4) {
    float4 v = *(float4*)&xtw[lane*68 + c4*4];
    #pragma unroll
    for (int j = 0; j < 10; ++j) {
      float4 wv = *(float4*)&w1mT[j*64 + c4*4];
      p[j] += v.x*wv.x + v.y*wv.y + v.z*wv.z + v.w*wv.w;
    }
  }
  float m = p[0];
  #pragma unroll
  for (int j = 1; j < 10; ++j) m = fmaxf(m, p[j]);
  float att[10]; float ssum = 0.f;
  #pragma unroll
  for (int j = 0; j < 10; ++j) { att[j] = __expf(p[j]-m); ssum += att[j]; }
  float inv = 1.f/ssum;
  #pragma unroll
  for (int j = 0; j < 10; ++j) att[j] *= inv;
  float w2r[10];
  #pragma unroll
  for (int j = 0; j < 10; ++j) w2r[j] = W2S[j*64 + lane];
  float* dst = memo + (((size_t)b*TT_ + s)*N_ + n0)*64;
  for (int r = 0; r < 64; ++r) {
    float o = 0.f;
    #pragma unroll
    for (int j = 0; j < 10; ++j) o += __shfl(att[j], r, 64) * w2r[j];
    dst[(size_t)r*64 + lane] = o;
  }
}

// ---------------- F1: time-mix+LN + in_proj GEMM + conv1d + silu + x_proj + dt + scan agg ----------------
__global__ __launch_bounds__(256) void f1_chunk(const float* __restrict__ x,
    const float* __restrict__ memo, const float* __restrict__ Wt,
    const float* __restrict__ ln_w, const float* __restrict__ ln_b,
    const float* __restrict__ W, const float* __restrict__ cw, const float* __restrict__ cb,
    const float* __restrict__ xpw, const float* __restrict__ dtw, const float* __restrict__ dtb,
    const float* __restrict__ A_log,
    float* __restrict__ uOut, float* __restrict__ xm, float* __restrict__ z,
    float* __restrict__ dt, float* __restrict__ Bm, float* __restrict__ Cm,
    float* __restrict__ aggP, float* __restrict__ aggS) {
  __shared__ float buf1[67*68];     // 18.2 KB: un rows (row-major) -> later xpT+pjs
  __shared__ float buf2[64*132];    // 33.8 KB: xv
  __shared__ float wts[T_*TT_];
  int tid = threadIdx.x;
  int cid = blockIdx.x;
  int b = cid / NCH_;
  int l0 = (cid % NCH_) * 64;
  size_t rbase = (size_t)b*L_ + l0;
  for (int i = tid; i < T_*TT_; i += 256) wts[i] = Wt[i];
  __syncthreads();
  // phase 0: u = x + sum_s wt[t,s]*memo[s]  (67 rows incl. 3-row halo), write u for main rows
  {
    const float* xb = x + (size_t)b*T_*N_*64;
    const float* mb = memo + (size_t)b*TT_*N_*64;
    for (int i = tid; i < 67*16; i += 256) {
      int rr = i >> 4, k4 = i & 15;
      int gl = l0 - 3 + rr;
      float4 acc = make_float4(0.f,0.f,0.f,0.f);
      if (gl >= 0) {
        int tg = gl >> 11, ng = gl & (N_-1);
        acc = *(const float4*)&xb[((size_t)tg*N_ + ng)*64 + k4*4];
        const float* mp = mb + (size_t)ng*64 + k4*4;
        const float* wrow = wts + tg*TT_;
        #pragma unroll
        for (int s = 0; s < TT_; ++s) {
          float4 mv = *(const float4*)&mp[(size_t)s*N_*64];
          float wv = wrow[s];
          acc.x += wv*mv.x; acc.y += wv*mv.y; acc.z += wv*mv.z; acc.w += wv*mv.w;
        }
        if (rr >= 3) *(float4*)&uOut[((size_t)b*L_ + gl)*64 + k4*4] = acc;
      }
      *(float4*)&buf1[rr*68 + k4*4] = acc;
    }
  }
  __syncthreads();
  // LN each valid row in place
  {
    int w = tid >> 6, lane = tid & 63;
    float lw = ln_w[lane], lb = ln_b[lane];
    for (int j = 0; j < 17; ++j) {
      int rr = j*4 + w;
      if (rr < 67 && (l0 - 3 + rr) >= 0) {
        float v = buf1[rr*68 + lane];
        float s1 = v, s2 = v*v;
        #pragma unroll
        for (int mm = 1; mm < 64; mm <<= 1) { s1 += __shfl_xor(s1, mm, 64); s2 += __shfl_xor(s2, mm, 64); }
        float mu = s1 * (1.f/64.f);
        float var = s2 * (1.f/64.f) - mu*mu;
        float iv = rsqrtf(var + 1e-5f);
        buf1[rr*68 + lane] = (v - mu) * iv * lw + lb;
      }
    }
  }
  __syncthreads();
  int c4 = tid & 31, rgrp = tid >> 5;
  // phase 1: merged xm-GEMM (11-row strip w/ halo) + z-GEMM, W from global (L2)
  float acc[11][4] = {};
  float acc2[8][4] = {};
  #pragma unroll 2
  for (int k = 0; k < 64; ++k) {
    float4 wx = *(const float4*)&W[(size_t)k*256 + c4*4];
    float4 wz = *(const float4*)&W[(size_t)k*256 + 128 + c4*4];
    float av[11];
    #pragma unroll
    for (int j = 0; j < 11; ++j) av[j] = buf1[(rgrp*8 + j)*68 + k];
    #pragma unroll
    for (int j = 0; j < 11; ++j) {
      acc[j][0] += av[j]*wx.x; acc[j][1] += av[j]*wx.y; acc[j][2] += av[j]*wx.z; acc[j][3] += av[j]*wx.w;
    }
    #pragma unroll
    for (int j = 0; j < 8; ++j) {
      float a = av[j+3];
      acc2[j][0] += a*wz.x; acc2[j][1] += a*wz.y; acc2[j][2] += a*wz.z; acc2[j][3] += a*wz.w;
    }
  }
  #pragma unroll
  for (int j = 0; j < 8; ++j) {
    float4 o; o.x=acc2[j][0]; o.y=acc2[j][1]; o.z=acc2[j][2]; o.w=acc2[j][3];
    *(float4*)&z[(rbase + rgrp*8 + j)*DI_ + c4*4] = o;
  }
  // conv + silu in registers
  float4 w0 = *(const float4*)&cw[0*DI_ + c4*4];
  float4 w1 = *(const float4*)&cw[1*DI_ + c4*4];
  float4 w2 = *(const float4*)&cw[2*DI_ + c4*4];
  float4 w3 = *(const float4*)&cw[3*DI_ + c4*4];
  float4 cbv = *(const float4*)&cb[c4*4];
  float sil[8][4];
  #pragma unroll
  for (int j = 0; j < 8; ++j) {
    float a0 = cbv.x + acc[j][0]*w0.x + acc[j+1][0]*w1.x + acc[j+2][0]*w2.x + acc[j+3][0]*w3.x;
    float a1 = cbv.y + acc[j][1]*w0.y + acc[j+1][1]*w1.y + acc[j+2][1]*w2.y + acc[j+3][1]*w3.y;
    float a2 = cbv.z + acc[j][2]*w0.z + acc[j+1][2]*w1.z + acc[j+2][2]*w2.z + acc[j+3][2]*w3.z;
    float a3 = cbv.w + acc[j][3]*w0.w + acc[j+1][3]*w1.w + acc[j+2][3]*w2.w + acc[j+3][3]*w3.w;
    sil[j][0] = a0 / (1.f + __expf(-a0));
    sil[j][1] = a1 / (1.f + __expf(-a1));
    sil[j][2] = a2 / (1.f + __expf(-a2));
    sil[j][3] = a3 / (1.f + __expf(-a3));
  }
  // phase 2: xv into buf2 (unused until now), xm to global; then xpT over buf1
  float* xv = buf2;
  #pragma unroll
  for (int j = 0; j < 8; ++j) {
    float4 o; o.x=sil[j][0]; o.y=sil[j][1]; o.z=sil[j][2]; o.w=sil[j][3];
    *(float4*)&xv[(rgrp*8+j)*132 + c4*4] = o;
    *(float4*)&xm[(rbase + rgrp*8 + j)*DI_ + c4*4] = o;
  }
  __syncthreads();                    // buf1 GEMM reads done; xv visible
  float* xpT = buf1;                  // [20][132]
  float* pjs = buf1 + 2688;           // [64][24]
  for (int i = tid; i < 2560; i += 256) {
    int c = i / 20, j = i % 20;
    xpT[j*132 + c] = xpw[i];
  }
  __syncthreads();
  // phase 3: x_proj mini-GEMM
  {
    int row = tid >> 2, q = tid & 3, j0 = q*5;
    float a5[5] = {0,0,0,0,0};
    for (int k4 = 0; k4 < 32; ++k4) {
      float4 a4 = *(float4*)&xv[row*132 + k4*4];
      #pragma unroll
      for (int jj = 0; jj < 5; ++jj) {
        float4 b4 = *(float4*)&xpT[(j0+jj)*132 + k4*4];
        a5[jj] += a4.x*b4.x + a4.y*b4.y + a4.z*b4.z + a4.w*b4.w;
      }
    }
    #pragma unroll
    for (int jj = 0; jj < 5; ++jj) pjs[row*24 + j0+jj] = a5[jj];
  }
  __syncthreads();
  // phase 4: dt epilogue + B/C store
  {
    float4 dw0 = *(const float4*)&dtw[0*DI_ + c4*4];
    float4 dw1 = *(const float4*)&dtw[1*DI_ + c4*4];
    float4 dw2 = *(const float4*)&dtw[2*DI_ + c4*4];
    float4 dw3 = *(const float4*)&dtw[3*DI_ + c4*4];
    float4 dbv = *(const float4*)&dtb[c4*4];
    #pragma unroll
    for (int j = 0; j < 8; ++j) {
      int row = rgrp*8 + j;
      float p0 = pjs[row*24+0], p1 = pjs[row*24+1], p2 = pjs[row*24+2], p3 = pjs[row*24+3];
      float a0 = dbv.x + p0*dw0.x + p1*dw1.x + p2*dw2.x + p3*dw3.x;
      float a1 = dbv.y + p0*dw0.y + p1*dw1.y + p2*dw2.y + p3*dw3.y;
      float a2 = dbv.z + p0*dw0.z + p1*dw1.z + p2*dw2.z + p3*dw3.z;
      float a3 = dbv.w + p0*dw0.w + p1*dw1.w + p2*dw2.w + p3*dw3.w;
      float4 o;
      o.x = (a0 > 15.f) ? a0 : __logf(1.f + __expf(a0));
      o.y = (a1 > 15.f) ? a1 : __logf(1.f + __expf(a1));
      o.z = (a2 > 15.f) ? a2 : __logf(1.f + __expf(a2));
      o.w = (a3 > 15.f) ? a3 : __logf(1.f + __expf(a3));
      *(float4*)&dt[(rbase + row)*DI_ + c4*4] = o;
    }
    int row = tid >> 2, q = tid & 3;
    float4 o;
    o.x = pjs[row*24 + 4 + q*4 + 0];
    o.y = pjs[row*24 + 4 + q*4 + 1];
    o.z = pjs[row*24 + 4 + q*4 + 2];
    o.w = pjs[row*24 + 4 + q*4 + 3];
    if (q < 2) *(float4*)&Bm[(rbase+row)*8 + q*4] = o;
    else       *(float4*)&Cm[(rbase+row)*8 + (q-2)*4] = o;
  }
  // phase 5: chunk-local scan aggregates
  {
    int d = tid & 127, q = tid >> 7;
    float4 av4 = *(const float4*)&A_log[d*8 + q*4];
    float a0 = -__expf(av4.x), a1 = -__expf(av4.y), a2 = -__expf(av4.z), a3 = -__expf(av4.w);
    float dtw0 = dtw[0*DI_+d], dtw1 = dtw[1*DI_+d], dtw2 = dtw[2*DI_+d], dtw3 = dtw[3*DI_+d];
    float dtbd = dtb[d];
    float P0=1.f,P1=1.f,P2=1.f,P3=1.f, S0=0.f,S1=0.f,S2=0.f,S3=0.f;
    for (int r = 0; r < 64; ++r) {
      float p0 = pjs[r*24+0], p1 = pjs[r*24+1], p2 = pjs[r*24+2], p3 = pjs[r*24+3];
      float aa = dtbd + p0*dtw0 + p1*dtw1 + p2*dtw2 + p3*dtw3;
      float dtv = (aa > 15.f) ? aa : __logf(1.f + __expf(aa));
      float dx = dtv * xv[r*132 + d];
      float b0 = pjs[r*24 + 4 + q*4 + 0];
      float b1 = pjs[r*24 + 4 + q*4 + 1];
      float b2 = pjs[r*24 + 4 + q*4 + 2];
      float b3 = pjs[r*24 + 4 + q*4 + 3];
      float e0 = __expf(dtv*a0), e1 = __expf(dtv*a1), e2 = __expf(dtv*a2), e3 = __expf(dtv*a3);
      P0*=e0; P1*=e1; P2*=e2; P3*=e3;
      S0 = e0*S0 + dx*b0; S1 = e1*S1 + dx*b1; S2 = e2*S2 + dx*b2; S3 = e3*S3 + dx*b3;
    }
    size_t o = (((size_t)cid)*128 + d)*8 + q*4;
    float4 pv; pv.x=P0; pv.y=P1; pv.z=P2; pv.w=P3;
    float4 sv; sv.x=S0; sv.y=S1; sv.z=S2; sv.w=S3;
    *(float4*)&aggP[o] = pv;
    *(float4*)&aggS[o] = sv;
  }
}

// ---------------- S2: serial combine across chunks ----------------
__global__ __launch_bounds__(256) void s2_scan_chunks(const float* __restrict__ aggP,
    const float* __restrict__ aggS, float* __restrict__ hIn) {
  int gidx = blockIdx.x*256 + threadIdx.x;   // (b, d*8+s)
  int b = gidx >> 10; int rem = gidx & 1023;
  float S = 0.f;
  #pragma unroll 8
  for (int ch = 0; ch < NCH_; ++ch) {
    size_t o = ((size_t)b*NCH_ + ch)*1024 + rem;
    hIn[o] = S;
    S = aggP[o]*S + aggS[o];
  }
}

// ---------------- F3: scan apply + gate + out_proj GEMM + residual ----------------
__global__ __launch_bounds__(256) void f3_scan_out(const float* __restrict__ dt,
    const float* __restrict__ xm, const float* __restrict__ z,
    const float* __restrict__ Bm, const float* __restrict__ Cm,
    const float* __restrict__ hIn, const float* __restrict__ A_log,
    const float* __restrict__ Dp, const float* __restrict__ Wo,
    const float* __restrict__ u, float* __restrict__ out) {
  __shared__ float y2t[64*132];   // 33.8 KB
  __shared__ float bc[64*16];     // 4 KB
  int tid = threadIdx.x;
  int cid = blockIdx.x;
  int b = cid / NCH_;
  int l0 = (cid % NCH_) * 64;
  size_t rbase = (size_t)b*L_ + l0;
  {
    int row = tid >> 2, q = tid & 3;
    float4 v = (q < 2) ? *(const float4*)&Bm[(rbase+row)*8 + q*4]
                       : *(const float4*)&Cm[(rbase+row)*8 + (q-2)*4];
    *(float4*)&bc[row*16 + q*4] = v;
  }
  __syncthreads();
  if (tid < 128) {
    int d = tid;
    float a[DS_], h[DS_];
    #pragma unroll
    for (int s = 0; s < DS_; ++s) a[s] = -__expf(A_log[d*8+s]);
    size_t o = (((size_t)cid)*128 + d)*8;
    #pragma unroll
    for (int s = 0; s < DS_; ++s) h[s] = hIn[o+s];
    float Dpd = Dp[d];
    #pragma unroll 4
    for (int r = 0; r < 64; ++r) {
      size_t rr = rbase + r;
      float dtv = dt[rr*DI_ + d];
      float xmv = xm[rr*DI_ + d];
      float zv  = z[rr*DI_ + d];
      float dx = dtv * xmv;
      float yv = xmv * Dpd;
      #pragma unroll
      for (int s = 0; s < DS_; ++s) {
        float dA = __expf(dtv * a[s]);
        h[s] = dA*h[s] + dx*bc[r*16 + s];
        yv += h[s]*bc[r*16 + 8 + s];
      }
      float sg = 1.f / (1.f + __expf(-zv));
      y2t[r*132 + d] = yv * zv * sg;
    }
  }
  __syncthreads();
  // out[64x64] = y2t[64x128] @ Wo[128x64] + u
  int tx = tid & 15, ty = tid >> 4;
  int col = tx*4;
  float acc[4][4] = {};
  #pragma unroll 2
  for (int k = 0; k < 128; ++k) {
    float4 bv = *(const float4*)&Wo[(size_t)k*64 + col];
    #pragma unroll
    for (int i = 0; i < 4; ++i) {
      float a = y2t[(ty*4+i)*132 + k];
      acc[i][0] += a*bv.x; acc[i][1] += a*bv.y; acc[i][2] += a*bv.z; acc[i][3] += a*bv.w;
    }
  }
  #pragma unroll
  for (int i = 0; i < 4; ++i) {
    size_t row = rbase + ty*4 + i;
    float4 uv = *(const float4*)&u[row*64 + col];
    float4 o;
    o.x = uv.x + acc[i][0]; o.y = uv.y + acc[i][1]; o.z = uv.z + acc[i][2]; o.w = uv.w + acc[i][3];
    *(float4*)&out[row*64 + col] = o;
  }
}

// ---------------- launch ----------------
extern "C" void kernel_launch(void* const* d_in, const int* in_sizes, int n_in,
                              void* d_out, int out_size, void* d_ws, size_t ws_size,
                              hipStream_t stream) {
  const float* x        = (const float*)d_in[0];
  const float* mconv_w  = (const float*)d_in[1];
  const float* mconv_b  = (const float*)d_in[2];
  const float* mWq      = (const float*)d_in[3];
  const float* mMk      = (const float*)d_in[4];
  const float* mMv      = (const float*)d_in[5];
  const float* memWq    = (const float*)d_in[6];
  const float* memM     = (const float*)d_in[7];
  const float* memWo    = (const float*)d_in[8];
  const float* memWt    = (const float*)d_in[9];
  const float* ln_w     = (const float*)d_in[10];
  const float* ln_b     = (const float*)d_in[11];
  const float* in_proj  = (const float*)d_in[12];
  const float* conv1d_w = (const float*)d_in[13];
  const float* conv1d_b = (const float*)d_in[14];
  const float* x_proj   = (const float*)d_in[15];
  const float* dt_w     = (const float*)d_in[16];
  const float* dt_b     = (const float*)d_in[17];
  const float* A_log    = (const float*)d_in[18];
  const float* Dp       = (const float*)d_in[19];
  const float* out_proj = (const float*)d_in[20];
  float* out = (float*)d_out;
  float* ws  = (float*)d_ws;

  float* W1      = ws + 0;          // 640
  float* W1m     = ws + 640;        // 640
  float* W2m     = ws + 1280;       // 640
  float* conv_raw= ws + 2048;       // 1,310,720
  float* memo    = ws + 1312768;    // 4,456,448
  float* u       = ws + 5769216;    // 3,145,728
  float* z       = ws + 8914944;    // 6,291,456
  float* xm      = ws + 15206400;   // 6,291,456
  float* dt      = ws + 21497856;   // 6,291,456
  float* Bm      = ws + 27789312;   // 393,216
  float* Cm      = ws + 28182528;   // 393,216
  float* aggP    = ws + 28575744;   // 786,432
  float* aggS    = ws + 29362176;   // 786,432
  float* hIn     = ws + 30148608;   // 786,432

  hipLaunchKernelGGL(k0_precomp, dim3(1), dim3(64), 0, stream,
                     mWq, mMk, memWq, memM, memWo, W1, W1m, W2m);
  hipLaunchKernelGGL(k1a_conv, dim3(32, 5, 2), dim3(256), 0, stream,
                     x, mconv_w, mconv_b, conv_raw);
  hipLaunchKernelGGL(k2m, dim3(272), dim3(256), 0, stream,
                     x, conv_raw, W1, mMv, W1m, W2m, memo);
  hipLaunchKernelGGL(f1_chunk, dim3(768), dim3(256), 0, stream,
                     x, memo, memWt, ln_w, ln_b, in_proj, conv1d_w, conv1d_b,
                     x_proj, dt_w, dt_b, A_log,
                     u, xm, z, dt, Bm, Cm, aggP, aggS);
  hipLaunchKernelGGL(s2_scan_chunks, dim3(8), dim3(256), 0, stream,
                     aggP, aggS, hIn);
  hipLaunchKernelGGL(f3_scan_out, dim3(768), dim3(256), 0, stream,
                     dt, xm, z, Bm, Cm, hIn, A_log, Dp, out_proj, u, out);
}